// Round 1
// baseline (212.846 us; speedup 1.0000x reference)
//
#include <hip/hip_runtime.h>

// LinearCrossAttentionAdd on MI355X (gfx950)
// Pipeline:
//  k0: w_qkv -> hi/lo bf16; lk/lq = cond @ w_l{k,q}^T + b
//  k1: x (b,c,n) f32 -> xt (b,n,c) bf16            [B^T layout for GEMM1]
//  k2: GEMM1 per batch: qkv = (Whi+Wlo) @ x. Epilogue:
//        q: +lq, softmax over d (shfl), store transposed hi/lo bf16 (b,n,256)
//        k: exp(k+lk) -> bf16 (b,256,n) in d_out-scratch; row-sums -> ksum (atomics)
//        v: bf16 (b,256,n) in d_out-scratch
//  k3: context partials: ctxU[d,e] = sum_n expk[d,n] v[e,n]  (MFMA, global frags)
//  k4: M[o,dg] = scale/ksum[dg] * sum_e w_out[o,e] ctx[d,e]  -> hi/lo bf16
//  k5: GEMM2 per batch: y = M @ qsoft + b_out -> d_out f32; sum/sumsq atomics
//  k6: layernorm in place (gamma/beta)

#define NB    16
#define DIM   256
#define NSP   4096
#define LED   128
#define HID   256
#define NHEAD 8
#define SCALE 0.17677669529663687f

typedef __bf16 bf16x8 __attribute__((ext_vector_type(8)));
typedef float f32x4 __attribute__((ext_vector_type(4)));
typedef unsigned short us8 __attribute__((ext_vector_type(8)));
typedef unsigned short us4 __attribute__((ext_vector_type(4)));

__device__ __forceinline__ unsigned short f2bf(float f){
  unsigned u = __builtin_bit_cast(unsigned, f);
  u += 0x7fffu + ((u >> 16) & 1u);
  return (unsigned short)(u >> 16);
}
__device__ __forceinline__ float bf2f(unsigned short h){
  unsigned u = ((unsigned)h) << 16;
  return __builtin_bit_cast(float, u);
}
__device__ __forceinline__ bf16x8 ldb8(const unsigned short* p){
  us8 r = *(const us8*)p;
  return __builtin_bit_cast(bf16x8, r);
}
__device__ __forceinline__ f32x4 mfma16(bf16x8 a, bf16x8 b, f32x4 c){
  return __builtin_amdgcn_mfma_f32_16x16x32_bf16(a, b, c, 0, 0, 0);
}

// ---------------- k0: prep (w split, lk/lq) ----------------
__global__ __launch_bounds__(256) void k0_prep(
    const float* __restrict__ wqkv, const float* __restrict__ cond,
    const float* __restrict__ wlk, const float* __restrict__ blk,
    const float* __restrict__ wlq, const float* __restrict__ blq,
    unsigned short* __restrict__ whi, unsigned short* __restrict__ wlo,
    float* __restrict__ lk, float* __restrict__ lq)
{
  const int idx = blockIdx.x*256 + threadIdx.x;
  if (idx < 768*256){
    const float w = wqkv[idx];
    const unsigned short h = f2bf(w);
    whi[idx] = h;
    wlo[idx] = f2bf(w - bf2f(h));
  } else {
    int i = idx - 768*256;           // < 8192
    const int which = (i >= NB*HID) ? 1 : 0;
    i &= (NB*HID - 1);
    const int b = i >> 8, o = i & 255;
    const float* wm = which ? wlq : wlk;
    const float* bs = which ? blq : blk;
    float s = bs[o];
    const float* c = cond + b*LED;
    const float* wr = wm + o*LED;
    for (int j=0;j<LED;j++) s += c[j]*wr[j];
    (which ? lq : lk)[i] = s;
  }
}

// ---------------- k1: transpose x -> bf16 ----------------
__global__ __launch_bounds__(256) void k1_txpose(
    const float* __restrict__ x, unsigned short* __restrict__ xt)
{
  __shared__ float tile[64][65];
  const int c0 = blockIdx.x*64, n0 = blockIdx.y*64, b = blockIdx.z;
  const int t = threadIdx.x;
  const int tr = t >> 6, tc = t & 63;
  const float* xp = x + ((size_t)b*DIM + c0)*NSP + n0;
  #pragma unroll
  for (int i=0;i<16;i++){
    const int cl = i*4 + tr;
    tile[cl][tc] = xp[(size_t)cl*NSP + tc];
  }
  __syncthreads();
  unsigned short* xtp = xt + ((size_t)b*NSP + n0)*DIM + c0;
  #pragma unroll
  for (int i=0;i<16;i++){
    const int nl = i*4 + tr;
    xtp[(size_t)nl*DIM + tc] = f2bf(tile[tc][nl]);
  }
}

// ---------------- k2: GEMM1 (qkv) with fused epilogues ----------------
__global__ __launch_bounds__(256) void k2_gemm1(
    const unsigned short* __restrict__ whi, const unsigned short* __restrict__ wlo,
    const unsigned short* __restrict__ xt,
    const float* __restrict__ lkv, const float* __restrict__ lqv,
    unsigned short* __restrict__ qh, unsigned short* __restrict__ ql,
    unsigned short* __restrict__ kexp, unsigned short* __restrict__ vout,
    float* __restrict__ ksum)
{
  alignas(16) __shared__ unsigned short Ah[128*64];
  alignas(16) __shared__ unsigned short Al[128*64];
  alignas(16) __shared__ unsigned short Bt[128*64];

  const int nt = blockIdx.x, mt = blockIdx.y, b = blockIdx.z;
  const int o0 = mt*128, n0 = nt*128;
  const int t = threadIdx.x, lane = t & 63, wv = t >> 6;
  const int wr = wv >> 1, wc = wv & 1;
  const int cl = lane & 15, g = lane >> 4;

  f32x4 acc[4][4];
  const f32x4 z4 = {0.f,0.f,0.f,0.f};
  #pragma unroll
  for (int m=0;m<4;m++)
    #pragma unroll
    for (int n=0;n<4;n++) acc[m][n] = z4;

  const unsigned short* xb = xt + ((size_t)b*NSP + n0)*DIM;
  const int srow = t >> 3;
  const int scol = (t & 7) << 3;

  for (int kt=0; kt<4; kt++){
    const int k0 = kt*64;
    __syncthreads();
    #pragma unroll
    for (int i=0;i<4;i++){
      const int r = i*32 + srow;
      *(us8*)&Ah[r*64 + scol] = *(const us8*)&whi[(size_t)(o0+r)*DIM + k0 + scol];
      *(us8*)&Al[r*64 + scol] = *(const us8*)&wlo[(size_t)(o0+r)*DIM + k0 + scol];
      *(us8*)&Bt[r*64 + scol] = *(const us8*)&xb[(size_t)r*DIM + k0 + scol];
    }
    __syncthreads();
    #pragma unroll
    for (int kk=0; kk<2; kk++){
      const int ko = kk*32 + g*8;
      bf16x8 a1[4], a2[4], bb[4];
      #pragma unroll
      for (int m=0;m<4;m++){
        const int row = wr*64 + m*16 + cl;
        a1[m] = ldb8(&Ah[row*64 + ko]);
        a2[m] = ldb8(&Al[row*64 + ko]);
      }
      #pragma unroll
      for (int n=0;n<4;n++){
        const int row = wc*64 + n*16 + cl;
        bb[n] = ldb8(&Bt[row*64 + ko]);
      }
      #pragma unroll
      for (int m=0;m<4;m++)
        #pragma unroll
        for (int n=0;n<4;n++){
          acc[m][n] = mfma16(a1[m], bb[n], acc[m][n]);
          acc[m][n] = mfma16(a2[m], bb[n], acc[m][n]);
        }
    }
  }

  if (mt < 2){
    // ---- Q region: +lq, softmax over d (32 rows per head), store transposed hi/lo
    float lqr[4][4];
    #pragma unroll
    for (int m=0;m<4;m++)
      #pragma unroll
      for (int i=0;i<4;i++)
        lqr[m][i] = lqv[b*HID + o0 + wr*64 + m*16 + g*4 + i];
    #pragma unroll
    for (int j=0;j<2;j++){
      #pragma unroll
      for (int nf=0;nf<4;nf++){
        float e[8]; float mx = -1e30f;
        #pragma unroll
        for (int mm=0;mm<2;mm++)
          #pragma unroll
          for (int i=0;i<4;i++){
            const int m = 2*j+mm;
            const float v = acc[m][nf][i] + lqr[m][i];
            e[mm*4+i] = v; mx = fmaxf(mx, v);
          }
        mx = fmaxf(mx, __shfl_xor(mx, 16));
        mx = fmaxf(mx, __shfl_xor(mx, 32));
        float s = 0.f;
        #pragma unroll
        for (int q2=0;q2<8;q2++){ e[q2] = __expf(e[q2]-mx); s += e[q2]; }
        s += __shfl_xor(s, 16);
        s += __shfl_xor(s, 32);
        const float r = 1.f/s;
        const int n = n0 + wc*64 + nf*16 + cl;
        #pragma unroll
        for (int mm=0;mm<2;mm++){
          const int m = 2*j+mm;
          const int dg0 = o0 + wr*64 + m*16 + g*4;
          us4 h4, l4;
          #pragma unroll
          for (int i=0;i<4;i++){
            const float v = e[mm*4+i]*r;
            const unsigned short hh = f2bf(v);
            h4[i] = hh;
            l4[i] = f2bf(v - bf2f(hh));
          }
          const size_t off = ((size_t)b*NSP + n)*HID + dg0;
          *(us4*)&qh[off] = h4;
          *(us4*)&ql[off] = l4;
        }
      }
    }
  } else if (mt < 4){
    // ---- K region: exp(k+lk), store bf16, row-sum atomics
    #pragma unroll
    for (int m=0;m<4;m++)
      #pragma unroll
      for (int i=0;i<4;i++){
        const int dg = (o0-256) + wr*64 + m*16 + g*4 + i;
        const float lkval = lkv[b*HID + dg];
        float s = 0.f;
        const size_t rowoff = ((size_t)b*HID + dg)*NSP + n0 + wc*64 + cl;
        #pragma unroll
        for (int nf=0;nf<4;nf++){
          const float v = __expf(acc[m][nf][i] + lkval);
          const unsigned short hh = f2bf(v);
          kexp[rowoff + nf*16] = hh;
          s += bf2f(hh);
        }
        s += __shfl_xor(s,1); s += __shfl_xor(s,2);
        s += __shfl_xor(s,4); s += __shfl_xor(s,8);
        if (cl == 0) atomicAdd(&ksum[b*HID + dg], s);
      }
  } else {
    // ---- V region: store bf16
    #pragma unroll
    for (int m=0;m<4;m++)
      #pragma unroll
      for (int i=0;i<4;i++){
        const int dg = (o0-512) + wr*64 + m*16 + g*4 + i;
        const size_t rowoff = ((size_t)b*HID + dg)*NSP + n0 + wc*64 + cl;
        #pragma unroll
        for (int nf=0;nf<4;nf++) vout[rowoff + nf*16] = f2bf(acc[m][nf][i]);
      }
  }
}

// ---------------- k3: context partials ----------------
__global__ __launch_bounds__(256) void k3_ctx(
    const unsigned short* __restrict__ kexp, const unsigned short* __restrict__ vv,
    float* __restrict__ ctxp)
{
  const int half = blockIdx.x, h = blockIdx.y, b = blockIdx.z;
  const int t = threadIdx.x, lane = t&63, wv = t>>6;
  const int cl = lane&15, g = lane>>4;
  const int nstart = half*2048 + wv*512;
  f32x4 acc[2][2];
  const f32x4 z4 = {0.f,0.f,0.f,0.f};
  acc[0][0]=z4; acc[0][1]=z4; acc[1][0]=z4; acc[1][1]=z4;
  const unsigned short* kb = kexp + ((size_t)b*HID + h*32)*NSP;
  const unsigned short* vb = vv   + ((size_t)b*HID + h*32)*NSP;
  for (int ks=0; ks<16; ks++){
    const int k = nstart + ks*32 + g*8;
    bf16x8 a0 = ldb8(&kb[(size_t)(cl)   *NSP + k]);
    bf16x8 a1 = ldb8(&kb[(size_t)(16+cl)*NSP + k]);
    bf16x8 b0 = ldb8(&vb[(size_t)(cl)   *NSP + k]);
    bf16x8 b1 = ldb8(&vb[(size_t)(16+cl)*NSP + k]);
    acc[0][0] = mfma16(a0,b0,acc[0][0]);
    acc[0][1] = mfma16(a0,b1,acc[0][1]);
    acc[1][0] = mfma16(a1,b0,acc[1][0]);
    acc[1][1] = mfma16(a1,b1,acc[1][1]);
  }
  float* outp = ctxp + ((((size_t)b*NHEAD + h)*2 + half)*4 + wv)*1024;
  #pragma unroll
  for (int dm=0;dm<2;dm++)
    #pragma unroll
    for (int em=0;em<2;em++)
      #pragma unroll
      for (int i=0;i<4;i++)
        outp[(dm*16 + g*4 + i)*32 + em*16 + cl] = acc[dm][em][i];
}

// ---------------- k4: M = scale/ksum * (w_out compose context), hi/lo ----------------
__global__ __launch_bounds__(256) void k4_m(
    const float* __restrict__ ctxp, const float* __restrict__ ksum,
    const float* __restrict__ wout,
    unsigned short* __restrict__ mhi, unsigned short* __restrict__ mlo)
{
  const int h = blockIdx.x, b = blockIdx.y;
  __shared__ float ctxl[32][32];
  __shared__ float rkn[32];
  const int t = threadIdx.x;
  const float* base = ctxp + (((size_t)b*NHEAD + h)*8)*1024;
  #pragma unroll
  for (int r=0;r<4;r++){
    const int de = r*256 + t;
    float s = 0.f;
    #pragma unroll
    for (int p=0;p<8;p++) s += base[p*1024 + de];
    ctxl[de>>5][de&31] = s;
  }
  if (t < 32) rkn[t] = SCALE / ksum[b*HID + h*32 + t];
  __syncthreads();
  float w[32];
  const float* wrow = wout + (size_t)t*HID + h*32;
  #pragma unroll
  for (int el=0;el<32;el++) w[el] = wrow[el];
  for (int dl=0; dl<32; dl++){
    float s = 0.f;
    #pragma unroll
    for (int el=0;el<32;el++) s += w[el]*ctxl[dl][el];
    s *= rkn[dl];
    const unsigned short hh = f2bf(s);
    const size_t off = ((size_t)b*HID + t)*HID + h*32 + dl;
    mhi[off] = hh;
    mlo[off] = f2bf(s - bf2f(hh));
  }
}

// ---------------- k5: GEMM2 (y = M @ qsoft + b_out) + stats ----------------
__global__ __launch_bounds__(256) void k5_gemm2(
    const unsigned short* __restrict__ mhi, const unsigned short* __restrict__ mlo,
    const unsigned short* __restrict__ qhp, const unsigned short* __restrict__ qlp,
    const float* __restrict__ bout,
    float* __restrict__ y, float* __restrict__ bsum, float* __restrict__ bssq)
{
  alignas(16) __shared__ unsigned short Ah[128*64];
  alignas(16) __shared__ unsigned short Al[128*64];
  alignas(16) __shared__ unsigned short Bh[128*64];
  alignas(16) __shared__ unsigned short Bl[128*64];
  __shared__ float red[8];

  const int nt = blockIdx.x, mt = blockIdx.y, b = blockIdx.z;
  const int o0 = mt*128, n0 = nt*128;
  const int t = threadIdx.x, lane = t&63, wv = t>>6;
  const int wr = wv>>1, wc = wv&1;
  const int cl = lane&15, g = lane>>4;

  f32x4 acc[4][4];
  const f32x4 z4 = {0.f,0.f,0.f,0.f};
  #pragma unroll
  for (int m=0;m<4;m++)
    #pragma unroll
    for (int n=0;n<4;n++) acc[m][n] = z4;

  const unsigned short* ab_h = mhi + (size_t)b*HID*HID;
  const unsigned short* ab_l = mlo + (size_t)b*HID*HID;
  const unsigned short* bb_h = qhp + ((size_t)b*NSP + n0)*HID;
  const unsigned short* bb_l = qlp + ((size_t)b*NSP + n0)*HID;
  const int srow = t>>3, scol = (t&7)<<3;

  for (int kt=0; kt<4; kt++){
    const int k0 = kt*64;
    __syncthreads();
    #pragma unroll
    for (int i=0;i<4;i++){
      const int r = i*32 + srow;
      *(us8*)&Ah[r*64+scol] = *(const us8*)&ab_h[(size_t)(o0+r)*HID + k0 + scol];
      *(us8*)&Al[r*64+scol] = *(const us8*)&ab_l[(size_t)(o0+r)*HID + k0 + scol];
      *(us8*)&Bh[r*64+scol] = *(const us8*)&bb_h[(size_t)r*HID + k0 + scol];
      *(us8*)&Bl[r*64+scol] = *(const us8*)&bb_l[(size_t)r*HID + k0 + scol];
    }
    __syncthreads();
    #pragma unroll
    for (int kk=0;kk<2;kk++){
      const int ko = kk*32 + g*8;
      bf16x8 ah[4], al[4], bh[4], bl[4];
      #pragma unroll
      for (int m=0;m<4;m++){
        const int row = wr*64 + m*16 + cl;
        ah[m] = ldb8(&Ah[row*64 + ko]);
        al[m] = ldb8(&Al[row*64 + ko]);
      }
      #pragma unroll
      for (int n=0;n<4;n++){
        const int row = wc*64 + n*16 + cl;
        bh[n] = ldb8(&Bh[row*64 + ko]);
        bl[n] = ldb8(&Bl[row*64 + ko]);
      }
      #pragma unroll
      for (int m=0;m<4;m++)
        #pragma unroll
        for (int n=0;n<4;n++){
          acc[m][n] = mfma16(ah[m], bh[n], acc[m][n]);
          acc[m][n] = mfma16(ah[m], bl[n], acc[m][n]);
          acc[m][n] = mfma16(al[m], bh[n], acc[m][n]);
        }
    }
  }

  float lsum = 0.f, lss = 0.f;
  #pragma unroll
  for (int m=0;m<4;m++)
    #pragma unroll
    for (int i=0;i<4;i++){
      const int o = o0 + wr*64 + m*16 + g*4 + i;
      const float bo = bout[o];
      const size_t rowoff = ((size_t)b*HID + o)*NSP + n0 + wc*64 + cl;
      #pragma unroll
      for (int nf=0;nf<4;nf++){
        const float v = acc[m][nf][i] + bo;
        y[rowoff + nf*16] = v;
        lsum += v; lss += v*v;
      }
    }
  #pragma unroll
  for (int sft=1; sft<64; sft<<=1){
    lsum += __shfl_xor(lsum, sft);
    lss  += __shfl_xor(lss,  sft);
  }
  if (lane == 0){ red[wv] = lsum; red[4+wv] = lss; }
  __syncthreads();
  if (t == 0){
    atomicAdd(&bsum[b], red[0]+red[1]+red[2]+red[3]);
    atomicAdd(&bssq[b], red[4]+red[5]+red[6]+red[7]);
  }
}

// ---------------- k6: layernorm in place ----------------
__global__ __launch_bounds__(256) void k6_norm(
    float* __restrict__ y, const float* __restrict__ bsum, const float* __restrict__ bssq,
    const float* __restrict__ gamma, const float* __restrict__ beta)
{
  const size_t idx = (size_t)blockIdx.x*256 + threadIdx.x;   // float4 index
  const int b = (int)(idx >> 18);
  const int o = (int)((idx >> 10) & 255);
  const float inv = 1.f/1048576.f;
  const float mean = bsum[b]*inv;
  const float var  = bssq[b]*inv - mean*mean;
  const float ri = rsqrtf(var + 1e-5f);
  const float ga = gamma[o]*ri;
  const float be = beta[o] - mean*ga;
  float4 v = ((float4*)y)[idx];
  v.x = v.x*ga + be; v.y = v.y*ga + be; v.z = v.z*ga + be; v.w = v.w*ga + be;
  ((float4*)y)[idx] = v;
}

// ---------------- workspace layout (bytes) ----------------
#define OFF_XT     0ull           // ushort [16][4096][256]  32MB
#define OFF_QH     33554432ull    // ushort [16][4096][256]  32MB
#define OFF_QL     67108864ull    // 32MB
#define OFF_CTXP   100663296ull   // float [16][8][2][4][1024] 4MB
#define OFF_MH     104857600ull   // ushort [16][256][256] 2MB
#define OFF_ML     106954752ull
#define OFF_LK     109051904ull   // float [16][256]
#define OFF_LQ     109068288ull
#define OFF_WHI    109084672ull   // ushort [768][256]
#define OFF_WLO    109477888ull
#define OFF_KSUM   109871104ull   // float [16][256]
#define OFF_BSUM   109887488ull   // float [16]
#define OFF_BSSQ   109887552ull   // float [16]
// total ~109.9 MB

extern "C" void kernel_launch(void* const* d_in, const int* in_sizes, int n_in,
                              void* d_out, int out_size, void* d_ws, size_t ws_size,
                              hipStream_t stream) {
  const float* x     = (const float*)d_in[0];
  const float* cond  = (const float*)d_in[1];
  const float* wqkv  = (const float*)d_in[2];
  const float* wlk   = (const float*)d_in[3];
  const float* blk   = (const float*)d_in[4];
  const float* wlq   = (const float*)d_in[5];
  const float* blq   = (const float*)d_in[6];
  const float* wout  = (const float*)d_in[7];
  const float* bout  = (const float*)d_in[8];
  const float* gamma = (const float*)d_in[9];
  const float* beta  = (const float*)d_in[10];

  char* ws = (char*)d_ws;
  unsigned short* xt   = (unsigned short*)(ws + OFF_XT);
  unsigned short* qh   = (unsigned short*)(ws + OFF_QH);
  unsigned short* ql   = (unsigned short*)(ws + OFF_QL);
  float*          ctxp = (float*)(ws + OFF_CTXP);
  unsigned short* mhi  = (unsigned short*)(ws + OFF_MH);
  unsigned short* mlo  = (unsigned short*)(ws + OFF_ML);
  float*          lk   = (float*)(ws + OFF_LK);
  float*          lq   = (float*)(ws + OFF_LQ);
  unsigned short* whi  = (unsigned short*)(ws + OFF_WHI);
  unsigned short* wlo  = (unsigned short*)(ws + OFF_WLO);
  float*          ksum = (float*)(ws + OFF_KSUM);
  float*          bsum = (float*)(ws + OFF_BSUM);
  float*          bssq = (float*)(ws + OFF_BSSQ);

  // d_out doubles as scratch for kexp/v (consumed by k3 before k5 writes y)
  unsigned short* kexp = (unsigned short*)d_out;
  unsigned short* vscr = (unsigned short*)d_out + 16777216;
  float*          y    = (float*)d_out;

  hipMemsetAsync(ws + OFF_KSUM, 0, 16384 + 128, stream);

  k0_prep  <<<800, 256, 0, stream>>>(wqkv, cond, wlk, blk, wlq, blq, whi, wlo, lk, lq);
  k1_txpose<<<dim3(4,64,16), 256, 0, stream>>>(x, xt);
  k2_gemm1 <<<dim3(32,6,16), 256, 0, stream>>>(whi, wlo, xt, lk, lq, qh, ql, kexp, vscr, ksum);
  k3_ctx   <<<dim3(2,8,16), 256, 0, stream>>>(kexp, vscr, ctxp);
  k4_m     <<<dim3(8,16), 256, 0, stream>>>(ctxp, ksum, wout, mhi, mlo);
  k5_gemm2 <<<dim3(32,2,16), 256, 0, stream>>>(mhi, mlo, qh, ql, bout, y, bsum, bssq);
  k6_norm  <<<16384, 256, 0, stream>>>(y, bsum, bssq, gamma, beta);
}

// Round 2
// 184.435 us; speedup vs baseline: 1.1540x; 1.1540x over previous
//
#include <hip/hip_runtime.h>

// LinearCrossAttentionAdd on MI355X (gfx950)
// Pipeline:
//  k0: w_qkv -> bf16; lk/lq = cond @ w_l{k,q}^T + b
//  k1: x (b,c,n) f32 -> xt (b,n,c) bf16            [B^T layout for GEMM1]
//  k2: GEMM1 per batch: qkv = W @ x (bf16, XOR-swizzled LDS). Epilogue:
//        q: +lq, softmax over d (shfl), store transposed hi/lo bf16 (b,n,256)
//        k: exp(k+lk) -> bf16 (b,256,n) in d_out-scratch; row-sums -> ksum (atomics)
//        v: bf16 (b,256,n) in d_out-scratch
//  k3: context partials: ctxU[d,e] = sum_n expk[d,n] v[e,n]  (MFMA, global frags)
//  k4: M[o,dg] = scale/ksum[dg] * sum_e w_out[o,e] ctx[d,e]  -> hi/lo bf16
//  k5: GEMM2 per batch: y = M @ qsoft + b_out -> d_out f32; sum/sumsq atomics
//  k6: layernorm in place (gamma/beta)

#define NB    16
#define DIM   256
#define NSP   4096
#define LED   128
#define HID   256
#define NHEAD 8
#define SCALE 0.17677669529663687f

typedef __bf16 bf16x8 __attribute__((ext_vector_type(8)));
typedef float f32x4 __attribute__((ext_vector_type(4)));
typedef unsigned short us8 __attribute__((ext_vector_type(8)));
typedef unsigned short us4 __attribute__((ext_vector_type(4)));

__device__ __forceinline__ unsigned short f2bf(float f){
  unsigned u = __builtin_bit_cast(unsigned, f);
  u += 0x7fffu + ((u >> 16) & 1u);
  return (unsigned short)(u >> 16);
}
__device__ __forceinline__ float bf2f(unsigned short h){
  unsigned u = ((unsigned)h) << 16;
  return __builtin_bit_cast(float, u);
}
__device__ __forceinline__ bf16x8 ldb8(const unsigned short* p){
  us8 r = *(const us8*)p;
  return __builtin_bit_cast(bf16x8, r);
}
__device__ __forceinline__ f32x4 mfma16(bf16x8 a, bf16x8 b, f32x4 c){
  return __builtin_amdgcn_mfma_f32_16x16x32_bf16(a, b, c, 0, 0, 0);
}

// ---------------- k0: prep (w -> bf16, lk/lq) ----------------
__global__ __launch_bounds__(256) void k0_prep(
    const float* __restrict__ wqkv, const float* __restrict__ cond,
    const float* __restrict__ wlk, const float* __restrict__ blk,
    const float* __restrict__ wlq, const float* __restrict__ blq,
    unsigned short* __restrict__ whi,
    float* __restrict__ lk, float* __restrict__ lq)
{
  const int idx = blockIdx.x*256 + threadIdx.x;
  if (idx < 768*256){
    whi[idx] = f2bf(wqkv[idx]);
  } else {
    int i = idx - 768*256;           // < 8192
    const int which = (i >= NB*HID) ? 1 : 0;
    i &= (NB*HID - 1);
    const int b = i >> 8, o = i & 255;
    const float* wm = which ? wlq : wlk;
    const float* bs = which ? blq : blk;
    float s = bs[o];
    const float* c = cond + b*LED;
    const float* wr = wm + o*LED;
    for (int j=0;j<LED;j++) s += c[j]*wr[j];
    (which ? lq : lk)[i] = s;
  }
}

// ---------------- k1: transpose x -> bf16 ----------------
__global__ __launch_bounds__(256) void k1_txpose(
    const float* __restrict__ x, unsigned short* __restrict__ xt)
{
  __shared__ float tile[64][65];
  const int c0 = blockIdx.x*64, n0 = blockIdx.y*64, b = blockIdx.z;
  const int t = threadIdx.x;
  const int tr = t >> 6, tc = t & 63;
  const float* xp = x + ((size_t)b*DIM + c0)*NSP + n0;
  #pragma unroll
  for (int i=0;i<16;i++){
    const int cl = i*4 + tr;
    tile[cl][tc] = xp[(size_t)cl*NSP + tc];
  }
  __syncthreads();
  unsigned short* xtp = xt + ((size_t)b*NSP + n0)*DIM + c0;
  #pragma unroll
  for (int i=0;i<16;i++){
    const int nl = i*4 + tr;
    xtp[(size_t)nl*DIM + tc] = f2bf(tile[tc][nl]);
  }
}

// ---------------- k2: GEMM1 (qkv) with fused epilogues ----------------
__global__ __launch_bounds__(256) void k2_gemm1(
    const unsigned short* __restrict__ whi,
    const unsigned short* __restrict__ xt,
    const float* __restrict__ lkv, const float* __restrict__ lqv,
    unsigned short* __restrict__ qh, unsigned short* __restrict__ ql,
    unsigned short* __restrict__ kexp, unsigned short* __restrict__ vout,
    float* __restrict__ ksum)
{
  // XOR-swizzled [128][64] ushort tiles: col' = col ^ ((row&7)<<3)
  alignas(16) __shared__ unsigned short Ah[128*64];
  alignas(16) __shared__ unsigned short Bt[128*64];

  const int nt = blockIdx.x, mt = blockIdx.y, b = blockIdx.z;
  const int o0 = mt*128, n0 = nt*128;
  const int t = threadIdx.x, lane = t & 63, wv = t >> 6;
  const int wr = wv >> 1, wc = wv & 1;
  const int cl = lane & 15, g = lane >> 4;

  f32x4 acc[4][4];
  const f32x4 z4 = {0.f,0.f,0.f,0.f};
  #pragma unroll
  for (int m=0;m<4;m++)
    #pragma unroll
    for (int n=0;n<4;n++) acc[m][n] = z4;

  const unsigned short* xb = xt + ((size_t)b*NSP + n0)*DIM;
  const int srow = t >> 3;
  const int scol = (t & 7) << 3;
  const int ssc  = scol ^ ((srow & 7) << 3);

  for (int kt=0; kt<4; kt++){
    const int k0 = kt*64;
    __syncthreads();
    #pragma unroll
    for (int i=0;i<4;i++){
      const int r = i*32 + srow;     // (r&7)==(srow&7): same swizzle each i
      *(us8*)&Ah[r*64 + ssc] = *(const us8*)&whi[(size_t)(o0+r)*DIM + k0 + scol];
      *(us8*)&Bt[r*64 + ssc] = *(const us8*)&xb[(size_t)r*DIM + k0 + scol];
    }
    __syncthreads();
    #pragma unroll
    for (int kk=0; kk<2; kk++){
      const int ko = kk*32 + g*8;
      const int kosw = ko ^ ((cl & 7) << 3);   // row&7 == cl&7 for all frag rows
      bf16x8 a1[4], bb[4];
      #pragma unroll
      for (int m=0;m<4;m++){
        const int row = wr*64 + m*16 + cl;
        a1[m] = ldb8(&Ah[row*64 + kosw]);
      }
      #pragma unroll
      for (int n=0;n<4;n++){
        const int row = wc*64 + n*16 + cl;
        bb[n] = ldb8(&Bt[row*64 + kosw]);
      }
      #pragma unroll
      for (int m=0;m<4;m++)
        #pragma unroll
        for (int n=0;n<4;n++)
          acc[m][n] = mfma16(a1[m], bb[n], acc[m][n]);
    }
  }

  if (mt < 2){
    // ---- Q region: +lq, softmax over d (32 rows per head), store transposed hi/lo
    float lqr[4][4];
    #pragma unroll
    for (int m=0;m<4;m++)
      #pragma unroll
      for (int i=0;i<4;i++)
        lqr[m][i] = lqv[b*HID + o0 + wr*64 + m*16 + g*4 + i];
    #pragma unroll
    for (int j=0;j<2;j++){
      #pragma unroll
      for (int nf=0;nf<4;nf++){
        float e[8]; float mx = -1e30f;
        #pragma unroll
        for (int mm=0;mm<2;mm++)
          #pragma unroll
          for (int i=0;i<4;i++){
            const int m = 2*j+mm;
            const float v = acc[m][nf][i] + lqr[m][i];
            e[mm*4+i] = v; mx = fmaxf(mx, v);
          }
        mx = fmaxf(mx, __shfl_xor(mx, 16));
        mx = fmaxf(mx, __shfl_xor(mx, 32));
        float s = 0.f;
        #pragma unroll
        for (int q2=0;q2<8;q2++){ e[q2] = __expf(e[q2]-mx); s += e[q2]; }
        s += __shfl_xor(s, 16);
        s += __shfl_xor(s, 32);
        const float r = 1.f/s;
        const int n = n0 + wc*64 + nf*16 + cl;
        #pragma unroll
        for (int mm=0;mm<2;mm++){
          const int m = 2*j+mm;
          const int dg0 = o0 + wr*64 + m*16 + g*4;
          us4 h4, l4;
          #pragma unroll
          for (int i=0;i<4;i++){
            const float v = e[mm*4+i]*r;
            const unsigned short hh = f2bf(v);
            h4[i] = hh;
            l4[i] = f2bf(v - bf2f(hh));
          }
          const size_t off = ((size_t)b*NSP + n)*HID + dg0;
          *(us4*)&qh[off] = h4;
          *(us4*)&ql[off] = l4;
        }
      }
    }
  } else if (mt < 4){
    // ---- K region: exp(k+lk), store bf16, row-sum atomics
    #pragma unroll
    for (int m=0;m<4;m++)
      #pragma unroll
      for (int i=0;i<4;i++){
        const int dg = (o0-256) + wr*64 + m*16 + g*4 + i;
        const float lkval = lkv[b*HID + dg];
        float s = 0.f;
        const size_t rowoff = ((size_t)b*HID + dg)*NSP + n0 + wc*64 + cl;
        #pragma unroll
        for (int nf=0;nf<4;nf++){
          const float v = __expf(acc[m][nf][i] + lkval);
          const unsigned short hh = f2bf(v);
          kexp[rowoff + nf*16] = hh;
          s += bf2f(hh);
        }
        s += __shfl_xor(s,1); s += __shfl_xor(s,2);
        s += __shfl_xor(s,4); s += __shfl_xor(s,8);
        if (cl == 0) atomicAdd(&ksum[b*HID + dg], s);
      }
  } else {
    // ---- V region: store bf16
    #pragma unroll
    for (int m=0;m<4;m++)
      #pragma unroll
      for (int i=0;i<4;i++){
        const int dg = (o0-512) + wr*64 + m*16 + g*4 + i;
        const size_t rowoff = ((size_t)b*HID + dg)*NSP + n0 + wc*64 + cl;
        #pragma unroll
        for (int nf=0;nf<4;nf++) vout[rowoff + nf*16] = f2bf(acc[m][nf][i]);
      }
  }
}

// ---------------- k3: context partials ----------------
__global__ __launch_bounds__(256) void k3_ctx(
    const unsigned short* __restrict__ kexp, const unsigned short* __restrict__ vv,
    float* __restrict__ ctxp)
{
  const int half = blockIdx.x, h = blockIdx.y, b = blockIdx.z;
  const int t = threadIdx.x, lane = t&63, wv = t>>6;
  const int cl = lane&15, g = lane>>4;
  const int nstart = half*2048 + wv*512;
  f32x4 acc[2][2];
  const f32x4 z4 = {0.f,0.f,0.f,0.f};
  acc[0][0]=z4; acc[0][1]=z4; acc[1][0]=z4; acc[1][1]=z4;
  const unsigned short* kb = kexp + ((size_t)b*HID + h*32)*NSP;
  const unsigned short* vb = vv   + ((size_t)b*HID + h*32)*NSP;
  for (int ks=0; ks<16; ks++){
    const int k = nstart + ks*32 + g*8;
    bf16x8 a0 = ldb8(&kb[(size_t)(cl)   *NSP + k]);
    bf16x8 a1 = ldb8(&kb[(size_t)(16+cl)*NSP + k]);
    bf16x8 b0 = ldb8(&vb[(size_t)(cl)   *NSP + k]);
    bf16x8 b1 = ldb8(&vb[(size_t)(16+cl)*NSP + k]);
    acc[0][0] = mfma16(a0,b0,acc[0][0]);
    acc[0][1] = mfma16(a0,b1,acc[0][1]);
    acc[1][0] = mfma16(a1,b0,acc[1][0]);
    acc[1][1] = mfma16(a1,b1,acc[1][1]);
  }
  float* outp = ctxp + ((((size_t)b*NHEAD + h)*2 + half)*4 + wv)*1024;
  #pragma unroll
  for (int dm=0;dm<2;dm++)
    #pragma unroll
    for (int em=0;em<2;em++)
      #pragma unroll
      for (int i=0;i<4;i++)
        outp[(dm*16 + g*4 + i)*32 + em*16 + cl] = acc[dm][em][i];
}

// ---------------- k4: M = scale/ksum * (w_out compose context), hi/lo ----------------
__global__ __launch_bounds__(256) void k4_m(
    const float* __restrict__ ctxp, const float* __restrict__ ksum,
    const float* __restrict__ wout,
    unsigned short* __restrict__ mhi, unsigned short* __restrict__ mlo)
{
  const int h = blockIdx.x, b = blockIdx.y;
  __shared__ float ctxl[32][32];
  __shared__ float rkn[32];
  const int t = threadIdx.x;
  const float* base = ctxp + (((size_t)b*NHEAD + h)*8)*1024;
  #pragma unroll
  for (int r=0;r<4;r++){
    const int de = r*256 + t;
    float s = 0.f;
    #pragma unroll
    for (int p=0;p<8;p++) s += base[p*1024 + de];
    ctxl[de>>5][de&31] = s;
  }
  if (t < 32) rkn[t] = SCALE / ksum[b*HID + h*32 + t];
  __syncthreads();
  float w[32];
  const float* wrow = wout + (size_t)t*HID + h*32;
  #pragma unroll
  for (int el=0;el<32;el++) w[el] = wrow[el];
  for (int dl=0; dl<32; dl++){
    float s = 0.f;
    #pragma unroll
    for (int el=0;el<32;el++) s += w[el]*ctxl[dl][el];
    s *= rkn[dl];
    const unsigned short hh = f2bf(s);
    const size_t off = ((size_t)b*HID + t)*HID + h*32 + dl;
    mhi[off] = hh;
    mlo[off] = f2bf(s - bf2f(hh));
  }
}

// ---------------- k5: GEMM2 (y = M @ qsoft + b_out) + stats ----------------
__global__ __launch_bounds__(256) void k5_gemm2(
    const unsigned short* __restrict__ mhi, const unsigned short* __restrict__ mlo,
    const unsigned short* __restrict__ qhp, const unsigned short* __restrict__ qlp,
    const float* __restrict__ bout,
    float* __restrict__ y, float* __restrict__ bsum, float* __restrict__ bssq)
{
  alignas(16) __shared__ unsigned short Ah[128*64];
  alignas(16) __shared__ unsigned short Al[128*64];
  alignas(16) __shared__ unsigned short Bh[128*64];
  alignas(16) __shared__ unsigned short Bl[128*64];
  __shared__ float red[8];

  const int nt = blockIdx.x, mt = blockIdx.y, b = blockIdx.z;
  const int o0 = mt*128, n0 = nt*128;
  const int t = threadIdx.x, lane = t&63, wv = t>>6;
  const int wr = wv>>1, wc = wv&1;
  const int cl = lane&15, g = lane>>4;

  f32x4 acc[4][4];
  const f32x4 z4 = {0.f,0.f,0.f,0.f};
  #pragma unroll
  for (int m=0;m<4;m++)
    #pragma unroll
    for (int n=0;n<4;n++) acc[m][n] = z4;

  const unsigned short* ab_h = mhi + (size_t)b*HID*HID;
  const unsigned short* ab_l = mlo + (size_t)b*HID*HID;
  const unsigned short* bb_h = qhp + ((size_t)b*NSP + n0)*HID;
  const unsigned short* bb_l = qlp + ((size_t)b*NSP + n0)*HID;
  const int srow = t>>3;
  const int scol = (t&7)<<3;
  const int ssc  = scol ^ ((srow & 7) << 3);

  for (int kt=0; kt<4; kt++){
    const int k0 = kt*64;
    __syncthreads();
    #pragma unroll
    for (int i=0;i<4;i++){
      const int r = i*32 + srow;
      *(us8*)&Ah[r*64+ssc] = *(const us8*)&ab_h[(size_t)(o0+r)*HID + k0 + scol];
      *(us8*)&Al[r*64+ssc] = *(const us8*)&ab_l[(size_t)(o0+r)*HID + k0 + scol];
      *(us8*)&Bh[r*64+ssc] = *(const us8*)&bb_h[(size_t)r*HID + k0 + scol];
      *(us8*)&Bl[r*64+ssc] = *(const us8*)&bb_l[(size_t)r*HID + k0 + scol];
    }
    __syncthreads();
    #pragma unroll
    for (int kk=0;kk<2;kk++){
      const int ko = kk*32 + g*8;
      const int kosw = ko ^ ((cl & 7) << 3);
      bf16x8 ah[4], al[4], bh[4], bl[4];
      #pragma unroll
      for (int m=0;m<4;m++){
        const int row = wr*64 + m*16 + cl;
        ah[m] = ldb8(&Ah[row*64 + kosw]);
        al[m] = ldb8(&Al[row*64 + kosw]);
      }
      #pragma unroll
      for (int n=0;n<4;n++){
        const int row = wc*64 + n*16 + cl;
        bh[n] = ldb8(&Bh[row*64 + kosw]);
        bl[n] = ldb8(&Bl[row*64 + kosw]);
      }
      #pragma unroll
      for (int m=0;m<4;m++)
        #pragma unroll
        for (int n=0;n<4;n++){
          acc[m][n] = mfma16(ah[m], bh[n], acc[m][n]);
          acc[m][n] = mfma16(ah[m], bl[n], acc[m][n]);
          acc[m][n] = mfma16(al[m], bh[n], acc[m][n]);
        }
    }
  }

  float lsum = 0.f, lss = 0.f;
  #pragma unroll
  for (int m=0;m<4;m++)
    #pragma unroll
    for (int i=0;i<4;i++){
      const int o = o0 + wr*64 + m*16 + g*4 + i;
      const float bo = bout[o];
      const size_t rowoff = ((size_t)b*HID + o)*NSP + n0 + wc*64 + cl;
      #pragma unroll
      for (int nf=0;nf<4;nf++){
        const float v = acc[m][nf][i] + bo;
        y[rowoff + nf*16] = v;
        lsum += v; lss += v*v;
      }
    }
  #pragma unroll
  for (int sft=1; sft<64; sft<<=1){
    lsum += __shfl_xor(lsum, sft);
    lss  += __shfl_xor(lss,  sft);
  }
  if (lane == 0){ red[wv] = lsum; red[4+wv] = lss; }
  __syncthreads();
  if (t == 0){
    atomicAdd(&bsum[b], red[0]+red[1]+red[2]+red[3]);
    atomicAdd(&bssq[b], red[4]+red[5]+red[6]+red[7]);
  }
}

// ---------------- k6: layernorm in place ----------------
__global__ __launch_bounds__(256) void k6_norm(
    float* __restrict__ y, const float* __restrict__ bsum, const float* __restrict__ bssq,
    const float* __restrict__ gamma, const float* __restrict__ beta)
{
  const size_t idx = (size_t)blockIdx.x*256 + threadIdx.x;   // float4 index
  const int b = (int)(idx >> 18);
  const int o = (int)((idx >> 10) & 255);
  const float inv = 1.f/1048576.f;
  const float mean = bsum[b]*inv;
  const float var  = bssq[b]*inv - mean*mean;
  const float ri = rsqrtf(var + 1e-5f);
  const float ga = gamma[o]*ri;
  const float be = beta[o] - mean*ga;
  float4 v = ((float4*)y)[idx];
  v.x = v.x*ga + be; v.y = v.y*ga + be; v.z = v.z*ga + be; v.w = v.w*ga + be;
  ((float4*)y)[idx] = v;
}

// ---------------- workspace layout (bytes) ----------------
#define OFF_XT     0ull           // ushort [16][4096][256]  32MB
#define OFF_QH     33554432ull    // ushort [16][4096][256]  32MB
#define OFF_QL     67108864ull    // 32MB
#define OFF_CTXP   100663296ull   // float [16][8][2][4][1024] 4MB
#define OFF_MH     104857600ull   // ushort [16][256][256] 2MB
#define OFF_ML     106954752ull
#define OFF_LK     109051904ull   // float [16][256]
#define OFF_LQ     109068288ull
#define OFF_WHI    109084672ull   // ushort [768][256]
#define OFF_KSUM   109871104ull   // float [16][256]
#define OFF_BSUM   109887488ull   // float [16]
#define OFF_BSSQ   109887552ull   // float [16]
// total ~109.9 MB

extern "C" void kernel_launch(void* const* d_in, const int* in_sizes, int n_in,
                              void* d_out, int out_size, void* d_ws, size_t ws_size,
                              hipStream_t stream) {
  const float* x     = (const float*)d_in[0];
  const float* cond  = (const float*)d_in[1];
  const float* wqkv  = (const float*)d_in[2];
  const float* wlk   = (const float*)d_in[3];
  const float* blk   = (const float*)d_in[4];
  const float* wlq   = (const float*)d_in[5];
  const float* blq   = (const float*)d_in[6];
  const float* wout  = (const float*)d_in[7];
  const float* bout  = (const float*)d_in[8];
  const float* gamma = (const float*)d_in[9];
  const float* beta  = (const float*)d_in[10];

  char* ws = (char*)d_ws;
  unsigned short* xt   = (unsigned short*)(ws + OFF_XT);
  unsigned short* qh   = (unsigned short*)(ws + OFF_QH);
  unsigned short* ql   = (unsigned short*)(ws + OFF_QL);
  float*          ctxp = (float*)(ws + OFF_CTXP);
  unsigned short* mhi  = (unsigned short*)(ws + OFF_MH);
  unsigned short* mlo  = (unsigned short*)(ws + OFF_ML);
  float*          lk   = (float*)(ws + OFF_LK);
  float*          lq   = (float*)(ws + OFF_LQ);
  unsigned short* whi  = (unsigned short*)(ws + OFF_WHI);
  float*          ksum = (float*)(ws + OFF_KSUM);
  float*          bsum = (float*)(ws + OFF_BSUM);
  float*          bssq = (float*)(ws + OFF_BSSQ);

  // d_out doubles as scratch for kexp/v (consumed by k3 before k5 writes y)
  unsigned short* kexp = (unsigned short*)d_out;
  unsigned short* vscr = (unsigned short*)d_out + 16777216;
  float*          y    = (float*)d_out;

  hipMemsetAsync(ws + OFF_KSUM, 0, 16384 + 128, stream);

  k0_prep  <<<800, 256, 0, stream>>>(wqkv, cond, wlk, blk, wlq, blq, whi, lk, lq);
  k1_txpose<<<dim3(4,64,16), 256, 0, stream>>>(x, xt);
  k2_gemm1 <<<dim3(32,6,16), 256, 0, stream>>>(whi, xt, lk, lq, qh, ql, kexp, vscr, ksum);
  k3_ctx   <<<dim3(2,8,16), 256, 0, stream>>>(kexp, vscr, ctxp);
  k4_m     <<<dim3(8,16), 256, 0, stream>>>(ctxp, ksum, wout, mhi, mlo);
  k5_gemm2 <<<dim3(32,2,16), 256, 0, stream>>>(mhi, mlo, qh, ql, bout, y, bsum, bssq);
  k6_norm  <<<16384, 256, 0, stream>>>(y, bsum, bssq, gamma, beta);
}

// Round 3
// 168.099 us; speedup vs baseline: 1.2662x; 1.0972x over previous
//
#include <hip/hip_runtime.h>

// LinearCrossAttentionAdd on MI355X (gfx950)
// Pipeline:
//  k0: w_qkv -> bf16; lk/lq = cond @ w_l{k,q}^T + b
//  k1: x (b,c,n) f32 -> xt (b,n,c) bf16            [B^T layout for GEMM1]
//  k2: GEMM1 per batch: qkv = W @ x. LDS-staged coalesced epilogues:
//        q: +lq, softmax over d, store [n][dg] bf16 (q-hi only)
//        k: exp(k+lk) -> bf16 [dg][n] in d_out-scratch; row-sums -> ksum
//        v: bf16 [dg][n] in d_out-scratch
//  k3: context partials: ctxU[d,e] = sum_n expk[d,n] v[e,n]  (MFMA)
//  k4: M[o,dg] = scale/ksum[dg] * sum_e w_out[o,e] ctx[d,e]  -> hi/lo bf16
//  k5a: GEMM2 stats pass: y = M @ q + b_out -> sum/sumsq atomics (no y write)
//  k5b: GEMM2 again + fused LayerNorm -> d_out f32 (LDS-staged stores)

#define NB    16
#define DIM   256
#define NSP   4096
#define LED   128
#define HID   256
#define NHEAD 8
#define SCALE 0.17677669529663687f

typedef __bf16 bf16x8 __attribute__((ext_vector_type(8)));
typedef float f32x4 __attribute__((ext_vector_type(4)));
typedef unsigned short us8 __attribute__((ext_vector_type(8)));
typedef unsigned short us4 __attribute__((ext_vector_type(4)));

__device__ __forceinline__ unsigned short f2bf(float f){
  unsigned u = __builtin_bit_cast(unsigned, f);
  u += 0x7fffu + ((u >> 16) & 1u);
  return (unsigned short)(u >> 16);
}
__device__ __forceinline__ float bf2f(unsigned short h){
  unsigned u = ((unsigned)h) << 16;
  return __builtin_bit_cast(float, u);
}
__device__ __forceinline__ bf16x8 ldb8(const unsigned short* p){
  us8 r = *(const us8*)p;
  return __builtin_bit_cast(bf16x8, r);
}
__device__ __forceinline__ f32x4 mfma16(bf16x8 a, bf16x8 b, f32x4 c){
  return __builtin_amdgcn_mfma_f32_16x16x32_bf16(a, b, c, 0, 0, 0);
}

// ---------------- k0: prep (w -> bf16, lk/lq) ----------------
__global__ __launch_bounds__(256) void k0_prep(
    const float* __restrict__ wqkv, const float* __restrict__ cond,
    const float* __restrict__ wlk, const float* __restrict__ blk,
    const float* __restrict__ wlq, const float* __restrict__ blq,
    unsigned short* __restrict__ whi,
    float* __restrict__ lk, float* __restrict__ lq)
{
  const int idx = blockIdx.x*256 + threadIdx.x;
  if (idx < 768*256){
    whi[idx] = f2bf(wqkv[idx]);
  } else {
    int i = idx - 768*256;           // < 8192
    const int which = (i >= NB*HID) ? 1 : 0;
    i &= (NB*HID - 1);
    const int b = i >> 8, o = i & 255;
    const float* wm = which ? wlq : wlk;
    const float* bs = which ? blq : blk;
    float s = bs[o];
    const float* c = cond + b*LED;
    const float* wr = wm + o*LED;
    for (int j=0;j<LED;j++) s += c[j]*wr[j];
    (which ? lq : lk)[i] = s;
  }
}

// ---------------- k1: transpose x -> bf16 ----------------
__global__ __launch_bounds__(256) void k1_txpose(
    const float* __restrict__ x, unsigned short* __restrict__ xt)
{
  __shared__ float tile[64][65];
  const int c0 = blockIdx.x*64, n0 = blockIdx.y*64, b = blockIdx.z;
  const int t = threadIdx.x;
  const int tr = t >> 6, tc = t & 63;
  const float* xp = x + ((size_t)b*DIM + c0)*NSP + n0;
  #pragma unroll
  for (int i=0;i<16;i++){
    const int cl = i*4 + tr;
    tile[cl][tc] = xp[(size_t)cl*NSP + tc];
  }
  __syncthreads();
  unsigned short* xtp = xt + ((size_t)b*NSP + n0)*DIM + c0;
  #pragma unroll
  for (int i=0;i<16;i++){
    const int nl = i*4 + tr;
    xtp[(size_t)nl*DIM + tc] = f2bf(tile[tc][nl]);
  }
}

// ---------------- k2: GEMM1 (qkv) with LDS-staged epilogues ----------------
// stage layout: [128 rows][136 ushort] (272 B row stride -> bank-spread, 16B-aligned)
__global__ __launch_bounds__(256) void k2_gemm1(
    const unsigned short* __restrict__ whi,
    const unsigned short* __restrict__ xt,
    const float* __restrict__ lkv, const float* __restrict__ lqv,
    unsigned short* __restrict__ qh,
    unsigned short* __restrict__ kexp, unsigned short* __restrict__ vout,
    float* __restrict__ ksum)
{
  __shared__ __align__(16) unsigned char smraw[34816];
  unsigned short* Ah  = (unsigned short*)smraw;            // [128*64]
  unsigned short* Bt  = (unsigned short*)(smraw + 16384);  // [128*64]
  unsigned short* stg = (unsigned short*)smraw;            // [128][136]

  const int nt = blockIdx.x, mt = blockIdx.y, b = blockIdx.z;
  const int o0 = mt*128, n0 = nt*128;
  const int t = threadIdx.x, lane = t & 63, wv = t >> 6;
  const int wr = wv >> 1, wc = wv & 1;
  const int cl = lane & 15, g = lane >> 4;

  f32x4 acc[4][4];
  const f32x4 z4 = {0.f,0.f,0.f,0.f};
  #pragma unroll
  for (int m=0;m<4;m++)
    #pragma unroll
    for (int n=0;n<4;n++) acc[m][n] = z4;

  const unsigned short* xb = xt + ((size_t)b*NSP + n0)*DIM;
  const int srow = t >> 3;
  const int scol = (t & 7) << 3;
  const int ssc  = scol ^ ((srow & 7) << 3);

  for (int kt=0; kt<4; kt++){
    const int k0 = kt*64;
    __syncthreads();
    #pragma unroll
    for (int i=0;i<4;i++){
      const int r = i*32 + srow;     // (r&7)==(srow&7): same swizzle each i
      *(us8*)&Ah[r*64 + ssc] = *(const us8*)&whi[(size_t)(o0+r)*DIM + k0 + scol];
      *(us8*)&Bt[r*64 + ssc] = *(const us8*)&xb[(size_t)r*DIM + k0 + scol];
    }
    __syncthreads();
    #pragma unroll
    for (int kk=0; kk<2; kk++){
      const int ko = kk*32 + g*8;
      const int kosw = ko ^ ((cl & 7) << 3);
      bf16x8 a1[4], bb[4];
      #pragma unroll
      for (int m=0;m<4;m++){
        const int row = wr*64 + m*16 + cl;
        a1[m] = ldb8(&Ah[row*64 + kosw]);
      }
      #pragma unroll
      for (int n=0;n<4;n++){
        const int row = wc*64 + n*16 + cl;
        bb[n] = ldb8(&Bt[row*64 + kosw]);
      }
      #pragma unroll
      for (int m=0;m<4;m++)
        #pragma unroll
        for (int n=0;n<4;n++)
          acc[m][n] = mfma16(a1[m], bb[n], acc[m][n]);
    }
  }

  __syncthreads();   // all LDS fragment reads complete before stage reuse

  if (mt < 2){
    // ---- Q: +lq, softmax over d; stage transposed [n_local][dg_local]
    float lqr[4][4];
    #pragma unroll
    for (int m=0;m<4;m++)
      #pragma unroll
      for (int i=0;i<4;i++)
        lqr[m][i] = lqv[b*HID + o0 + wr*64 + m*16 + g*4 + i];
    #pragma unroll
    for (int j=0;j<2;j++){
      #pragma unroll
      for (int nf=0;nf<4;nf++){
        float e[8]; float mx = -1e30f;
        #pragma unroll
        for (int mm=0;mm<2;mm++)
          #pragma unroll
          for (int i=0;i<4;i++){
            const int m = 2*j+mm;
            const float v = acc[m][nf][i] + lqr[m][i];
            e[mm*4+i] = v; mx = fmaxf(mx, v);
          }
        mx = fmaxf(mx, __shfl_xor(mx, 16));
        mx = fmaxf(mx, __shfl_xor(mx, 32));
        float s = 0.f;
        #pragma unroll
        for (int q2=0;q2<8;q2++){ e[q2] = __expf(e[q2]-mx); s += e[q2]; }
        s += __shfl_xor(s, 16);
        s += __shfl_xor(s, 32);
        const float r = 1.f/s;
        const int n_local = wc*64 + nf*16 + cl;
        #pragma unroll
        for (int mm=0;mm<2;mm++){
          const int dg_local = wr*64 + (2*j+mm)*16 + g*4;
          us4 h4;
          #pragma unroll
          for (int i=0;i<4;i++) h4[i] = f2bf(e[mm*4+i]*r);
          *(us4*)&stg[n_local*136 + dg_local] = h4;
        }
      }
    }
    __syncthreads();
    unsigned short* qbase = qh + ((size_t)b*NSP + n0)*HID + o0;
    #pragma unroll
    for (int i2=0;i2<8;i2++){
      const int n_local = wv*32 + i2*4 + (lane>>4);
      const int dg8 = (lane&15)*8;
      us8 val = *(const us8*)&stg[n_local*136 + dg8];
      *(us8*)&qbase[(size_t)n_local*HID + dg8] = val;
    }
  } else {
    // ---- K / V: stage [dg_local][n_local]
    const int isK = (mt < 4);
    const int dgbase = isK ? (mt-2)*128 : (mt-4)*128;
    #pragma unroll
    for (int m=0;m<4;m++)
      #pragma unroll
      for (int i=0;i<4;i++){
        const int dg_local = wr*64 + m*16 + g*4 + i;
        const int nb0 = wc*64 + cl;
        if (isK){
          const float lkval = lkv[b*HID + dgbase + dg_local];
          float s = 0.f;
          #pragma unroll
          for (int nf=0;nf<4;nf++){
            const float v = __expf(acc[m][nf][i] + lkval);
            const unsigned short hh = f2bf(v);
            stg[dg_local*136 + nb0 + nf*16] = hh;
            s += bf2f(hh);
          }
          s += __shfl_xor(s,1); s += __shfl_xor(s,2);
          s += __shfl_xor(s,4); s += __shfl_xor(s,8);
          if (cl == 0) atomicAdd(&ksum[b*HID + dgbase + dg_local], s);
        } else {
          #pragma unroll
          for (int nf=0;nf<4;nf++)
            stg[dg_local*136 + nb0 + nf*16] = f2bf(acc[m][nf][i]);
        }
      }
    __syncthreads();
    unsigned short* obase = (isK ? kexp : vout) + ((size_t)b*HID + dgbase)*NSP + n0;
    #pragma unroll
    for (int i2=0;i2<8;i2++){
      const int dg_local = wv*32 + i2*4 + (lane>>4);
      const int n8 = (lane&15)*8;
      us8 val = *(const us8*)&stg[dg_local*136 + n8];
      *(us8*)&obase[(size_t)dg_local*NSP + n8] = val;
    }
  }
}

// ---------------- k3: context partials ----------------
__global__ __launch_bounds__(256) void k3_ctx(
    const unsigned short* __restrict__ kexp, const unsigned short* __restrict__ vv,
    float* __restrict__ ctxp)
{
  const int half = blockIdx.x, h = blockIdx.y, b = blockIdx.z;
  const int t = threadIdx.x, lane = t&63, wv = t>>6;
  const int cl = lane&15, g = lane>>4;
  const int nstart = half*2048 + wv*512;
  f32x4 acc[2][2];
  const f32x4 z4 = {0.f,0.f,0.f,0.f};
  acc[0][0]=z4; acc[0][1]=z4; acc[1][0]=z4; acc[1][1]=z4;
  const unsigned short* kb = kexp + ((size_t)b*HID + h*32)*NSP;
  const unsigned short* vb = vv   + ((size_t)b*HID + h*32)*NSP;
  for (int ks=0; ks<16; ks++){
    const int k = nstart + ks*32 + g*8;
    bf16x8 a0 = ldb8(&kb[(size_t)(cl)   *NSP + k]);
    bf16x8 a1 = ldb8(&kb[(size_t)(16+cl)*NSP + k]);
    bf16x8 b0 = ldb8(&vb[(size_t)(cl)   *NSP + k]);
    bf16x8 b1 = ldb8(&vb[(size_t)(16+cl)*NSP + k]);
    acc[0][0] = mfma16(a0,b0,acc[0][0]);
    acc[0][1] = mfma16(a0,b1,acc[0][1]);
    acc[1][0] = mfma16(a1,b0,acc[1][0]);
    acc[1][1] = mfma16(a1,b1,acc[1][1]);
  }
  float* outp = ctxp + ((((size_t)b*NHEAD + h)*2 + half)*4 + wv)*1024;
  #pragma unroll
  for (int dm=0;dm<2;dm++)
    #pragma unroll
    for (int em=0;em<2;em++)
      #pragma unroll
      for (int i=0;i<4;i++)
        outp[(dm*16 + g*4 + i)*32 + em*16 + cl] = acc[dm][em][i];
}

// ---------------- k4: M = scale/ksum * (w_out compose context), hi/lo ----------------
__global__ __launch_bounds__(256) void k4_m(
    const float* __restrict__ ctxp, const float* __restrict__ ksum,
    const float* __restrict__ wout,
    unsigned short* __restrict__ mhi, unsigned short* __restrict__ mlo)
{
  const int h = blockIdx.x, b = blockIdx.y;
  __shared__ float ctxl[32][32];
  __shared__ float rkn[32];
  const int t = threadIdx.x;
  const float* base = ctxp + (((size_t)b*NHEAD + h)*8)*1024;
  #pragma unroll
  for (int r=0;r<4;r++){
    const int de = r*256 + t;
    float s = 0.f;
    #pragma unroll
    for (int p=0;p<8;p++) s += base[p*1024 + de];
    ctxl[de>>5][de&31] = s;
  }
  if (t < 32) rkn[t] = SCALE / ksum[b*HID + h*32 + t];
  __syncthreads();
  float w[32];
  const float* wrow = wout + (size_t)t*HID + h*32;
  #pragma unroll
  for (int el=0;el<32;el++) w[el] = wrow[el];
  for (int dl=0; dl<32; dl++){
    float s = 0.f;
    #pragma unroll
    for (int el=0;el<32;el++) s += w[el]*ctxl[dl][el];
    s *= rkn[dl];
    const unsigned short hh = f2bf(s);
    const size_t off = ((size_t)b*HID + t)*HID + h*32 + dl;
    mhi[off] = hh;
    mlo[off] = f2bf(s - bf2f(hh));
  }
}

// ---------------- k5a: GEMM2 stats pass (no y write) ----------------
__global__ __launch_bounds__(256) void k5a_stats(
    const unsigned short* __restrict__ mhi, const unsigned short* __restrict__ mlo,
    const unsigned short* __restrict__ qhp, const float* __restrict__ bout,
    float* __restrict__ bsum, float* __restrict__ bssq)
{
  alignas(16) __shared__ unsigned short Ah[128*64];
  alignas(16) __shared__ unsigned short Al[128*64];
  alignas(16) __shared__ unsigned short Bh[128*64];
  __shared__ float red[8];

  const int nt = blockIdx.x, mt = blockIdx.y, b = blockIdx.z;
  const int o0 = mt*128, n0 = nt*128;
  const int t = threadIdx.x, lane = t&63, wv = t>>6;
  const int wr = wv>>1, wc = wv&1;
  const int cl = lane&15, g = lane>>4;

  f32x4 acc[4][4];
  const f32x4 z4 = {0.f,0.f,0.f,0.f};
  #pragma unroll
  for (int m=0;m<4;m++)
    #pragma unroll
    for (int n=0;n<4;n++) acc[m][n] = z4;

  const unsigned short* ab_h = mhi + (size_t)b*HID*HID;
  const unsigned short* ab_l = mlo + (size_t)b*HID*HID;
  const unsigned short* bb_h = qhp + ((size_t)b*NSP + n0)*HID;
  const int srow = t>>3;
  const int scol = (t&7)<<3;
  const int ssc  = scol ^ ((srow & 7) << 3);

  for (int kt=0; kt<4; kt++){
    const int k0 = kt*64;
    __syncthreads();
    #pragma unroll
    for (int i=0;i<4;i++){
      const int r = i*32 + srow;
      *(us8*)&Ah[r*64+ssc] = *(const us8*)&ab_h[(size_t)(o0+r)*HID + k0 + scol];
      *(us8*)&Al[r*64+ssc] = *(const us8*)&ab_l[(size_t)(o0+r)*HID + k0 + scol];
      *(us8*)&Bh[r*64+ssc] = *(const us8*)&bb_h[(size_t)r*HID + k0 + scol];
    }
    __syncthreads();
    #pragma unroll
    for (int kk=0;kk<2;kk++){
      const int ko = kk*32 + g*8;
      const int kosw = ko ^ ((cl & 7) << 3);
      bf16x8 ah[4], al[4], bh[4];
      #pragma unroll
      for (int m=0;m<4;m++){
        const int row = wr*64 + m*16 + cl;
        ah[m] = ldb8(&Ah[row*64 + kosw]);
        al[m] = ldb8(&Al[row*64 + kosw]);
      }
      #pragma unroll
      for (int n=0;n<4;n++){
        const int row = wc*64 + n*16 + cl;
        bh[n] = ldb8(&Bh[row*64 + kosw]);
      }
      #pragma unroll
      for (int m=0;m<4;m++)
        #pragma unroll
        for (int n=0;n<4;n++){
          acc[m][n] = mfma16(ah[m], bh[n], acc[m][n]);
          acc[m][n] = mfma16(al[m], bh[n], acc[m][n]);
        }
    }
  }

  float lsum = 0.f, lss = 0.f;
  #pragma unroll
  for (int m=0;m<4;m++)
    #pragma unroll
    for (int i=0;i<4;i++){
      const float bo = bout[o0 + wr*64 + m*16 + g*4 + i];
      #pragma unroll
      for (int nf=0;nf<4;nf++){
        const float v = acc[m][nf][i] + bo;
        lsum += v; lss += v*v;
      }
    }
  #pragma unroll
  for (int sft=1; sft<64; sft<<=1){
    lsum += __shfl_xor(lsum, sft);
    lss  += __shfl_xor(lss,  sft);
  }
  if (lane == 0){ red[wv] = lsum; red[4+wv] = lss; }
  __syncthreads();
  if (t == 0){
    atomicAdd(&bsum[b], red[0]+red[1]+red[2]+red[3]);
    atomicAdd(&bssq[b], red[4]+red[5]+red[6]+red[7]);
  }
}

// ---------------- k5b: GEMM2 + fused LayerNorm write ----------------
__global__ __launch_bounds__(256) void k5b_write(
    const unsigned short* __restrict__ mhi, const unsigned short* __restrict__ mlo,
    const unsigned short* __restrict__ qhp, const float* __restrict__ bout,
    const float* __restrict__ bsum, const float* __restrict__ bssq,
    const float* __restrict__ gamma, const float* __restrict__ beta,
    float* __restrict__ out)
{
  __shared__ __align__(16) unsigned char smraw[49152];
  unsigned short* Ah = (unsigned short*)smraw;             // [128*64]
  unsigned short* Al = (unsigned short*)(smraw + 16384);
  unsigned short* Bh = (unsigned short*)(smraw + 32768);
  float* stg = (float*)smraw;                              // [64][132]

  const int nt = blockIdx.x, mt = blockIdx.y, b = blockIdx.z;
  const int o0 = mt*128, n0 = nt*128;
  const int t = threadIdx.x, lane = t&63, wv = t>>6;
  const int wr = wv>>1, wc = wv&1;
  const int cl = lane&15, g = lane>>4;

  f32x4 acc[4][4];
  const f32x4 z4 = {0.f,0.f,0.f,0.f};
  #pragma unroll
  for (int m=0;m<4;m++)
    #pragma unroll
    for (int n=0;n<4;n++) acc[m][n] = z4;

  const unsigned short* ab_h = mhi + (size_t)b*HID*HID;
  const unsigned short* ab_l = mlo + (size_t)b*HID*HID;
  const unsigned short* bb_h = qhp + ((size_t)b*NSP + n0)*HID;
  const int srow = t>>3;
  const int scol = (t&7)<<3;
  const int ssc  = scol ^ ((srow & 7) << 3);

  for (int kt=0; kt<4; kt++){
    const int k0 = kt*64;
    __syncthreads();
    #pragma unroll
    for (int i=0;i<4;i++){
      const int r = i*32 + srow;
      *(us8*)&Ah[r*64+ssc] = *(const us8*)&ab_h[(size_t)(o0+r)*HID + k0 + scol];
      *(us8*)&Al[r*64+ssc] = *(const us8*)&ab_l[(size_t)(o0+r)*HID + k0 + scol];
      *(us8*)&Bh[r*64+ssc] = *(const us8*)&bb_h[(size_t)r*HID + k0 + scol];
    }
    __syncthreads();
    #pragma unroll
    for (int kk=0;kk<2;kk++){
      const int ko = kk*32 + g*8;
      const int kosw = ko ^ ((cl & 7) << 3);
      bf16x8 ah[4], al[4], bh[4];
      #pragma unroll
      for (int m=0;m<4;m++){
        const int row = wr*64 + m*16 + cl;
        ah[m] = ldb8(&Ah[row*64 + kosw]);
        al[m] = ldb8(&Al[row*64 + kosw]);
      }
      #pragma unroll
      for (int n=0;n<4;n++){
        const int row = wc*64 + n*16 + cl;
        bh[n] = ldb8(&Bh[row*64 + kosw]);
      }
      #pragma unroll
      for (int m=0;m<4;m++)
        #pragma unroll
        for (int n=0;n<4;n++){
          acc[m][n] = mfma16(ah[m], bh[n], acc[m][n]);
          acc[m][n] = mfma16(al[m], bh[n], acc[m][n]);
        }
    }
  }

  // LN coefficients: out = acc*ga + (beta + (bout-mean)*ga)
  const float inv = 1.f/1048576.f;
  const float mean = bsum[b]*inv;
  const float var  = bssq[b]*inv - mean*mean;
  const float ri = rsqrtf(var + 1e-5f);
  float gav[4][4], bev[4][4];
  #pragma unroll
  for (int m=0;m<4;m++)
    #pragma unroll
    for (int i=0;i<4;i++){
      const int o = o0 + wr*64 + m*16 + g*4 + i;
      const float ga = gamma[o]*ri;
      gav[m][i] = ga;
      bev[m][i] = beta[o] + (bout[o]-mean)*ga;
    }

  // two passes over m-halves; stage [64 rows][132 f32] then 512B-segment stores
  #pragma unroll
  for (int p=0;p<2;p++){
    __syncthreads();
    #pragma unroll
    for (int mm=0;mm<2;mm++){
      const int m = 2*p+mm;
      #pragma unroll
      for (int nf=0;nf<4;nf++)
        #pragma unroll
        for (int i=0;i<4;i++){
          const int lr = wr*32 + mm*16 + g*4 + i;
          stg[lr*132 + wc*64 + nf*16 + cl] = acc[m][nf][i]*gav[m][i] + bev[m][i];
        }
    }
    __syncthreads();
    #pragma unroll
    for (int i2=0;i2<8;i2++){
      const int lr = wv*16 + i2*2 + (lane>>5);
      const int colw = (lane&31)*4;
      f32x4 v = *(const f32x4*)&stg[lr*132 + colw];
      const int dg = o0 + (lr>>5)*64 + p*32 + (lr&31);
      *(f32x4*)&out[((size_t)b*HID + dg)*NSP + n0 + colw] = v;
    }
  }
}

// ---------------- workspace layout (bytes) ----------------
#define OFF_XT     0ull           // ushort [16][4096][256]  32MB
#define OFF_QH     33554432ull    // ushort [16][4096][256]  32MB
#define OFF_CTXP   100663296ull   // float [16][8][2][4][1024] 4MB
#define OFF_MH     104857600ull   // ushort [16][256][256] 2MB
#define OFF_ML     106954752ull
#define OFF_LK     109051904ull   // float [16][256]
#define OFF_LQ     109068288ull
#define OFF_WHI    109084672ull   // ushort [768][256]
#define OFF_KSUM   109871104ull   // float [16][256]
#define OFF_BSUM   109887488ull   // float [16]
#define OFF_BSSQ   109887552ull   // float [16]

extern "C" void kernel_launch(void* const* d_in, const int* in_sizes, int n_in,
                              void* d_out, int out_size, void* d_ws, size_t ws_size,
                              hipStream_t stream) {
  const float* x     = (const float*)d_in[0];
  const float* cond  = (const float*)d_in[1];
  const float* wqkv  = (const float*)d_in[2];
  const float* wlk   = (const float*)d_in[3];
  const float* blk   = (const float*)d_in[4];
  const float* wlq   = (const float*)d_in[5];
  const float* blq   = (const float*)d_in[6];
  const float* wout  = (const float*)d_in[7];
  const float* bout  = (const float*)d_in[8];
  const float* gamma = (const float*)d_in[9];
  const float* beta  = (const float*)d_in[10];

  char* ws = (char*)d_ws;
  unsigned short* xt   = (unsigned short*)(ws + OFF_XT);
  unsigned short* qh   = (unsigned short*)(ws + OFF_QH);
  float*          ctxp = (float*)(ws + OFF_CTXP);
  unsigned short* mhi  = (unsigned short*)(ws + OFF_MH);
  unsigned short* mlo  = (unsigned short*)(ws + OFF_ML);
  float*          lk   = (float*)(ws + OFF_LK);
  float*          lq   = (float*)(ws + OFF_LQ);
  unsigned short* whi  = (unsigned short*)(ws + OFF_WHI);
  float*          ksum = (float*)(ws + OFF_KSUM);
  float*          bsum = (float*)(ws + OFF_BSUM);
  float*          bssq = (float*)(ws + OFF_BSSQ);

  // d_out doubles as scratch for kexp/v (consumed by k3 before k5b writes y)
  unsigned short* kexp = (unsigned short*)d_out;
  unsigned short* vscr = (unsigned short*)d_out + 16777216;
  float*          y    = (float*)d_out;

  hipMemsetAsync(ws + OFF_KSUM, 0, 16384 + 128, stream);

  k0_prep  <<<800, 256, 0, stream>>>(wqkv, cond, wlk, blk, wlq, blq, whi, lk, lq);
  k1_txpose<<<dim3(4,64,16), 256, 0, stream>>>(x, xt);
  k2_gemm1 <<<dim3(32,6,16), 256, 0, stream>>>(whi, xt, lk, lq, qh, kexp, vscr, ksum);
  k3_ctx   <<<dim3(2,8,16), 256, 0, stream>>>(kexp, vscr, ctxp);
  k4_m     <<<dim3(8,16), 256, 0, stream>>>(ctxp, ksum, wout, mhi, mlo);
  k5a_stats<<<dim3(32,2,16), 256, 0, stream>>>(mhi, mlo, qh, bout, bsum, bssq);
  k5b_write<<<dim3(32,2,16), 256, 0, stream>>>(mhi, mlo, qh, bout, bsum, bssq, gamma, beta, y);
}

// Round 4
// 163.945 us; speedup vs baseline: 1.2983x; 1.0253x over previous
//
#include <hip/hip_runtime.h>

// LinearCrossAttentionAdd on MI355X (gfx950)
// Pipeline:
//  k0: w_qkv -> bf16; lk/lq = cond @ w_l{k,q}^T + b
//  k1: x (b,c,n) f32 -> xt (b,n,c) bf16            [B^T layout for GEMM1]
//  k2: GEMM1 per batch: qkv = W @ x. global_load_lds staging (pre-swizzled src).
//        q: +lq, softmax over d, store [n][dg] bf16 (q-hi only)
//        k: exp(k+lk) -> bf16 [dg][n] in d_out-scratch; row-sums -> ksum
//        v: bf16 [dg][n] in d_out-scratch
//  k3: context partials: ctxU[d,e] = sum_n expk[d,n] v[e,n]  (MFMA)
//  k4: M[o,dg] = scale/ksum[dg] * sum_e w_out[o,e] ctx[d,e]  -> hi/lo bf16
//  k5a: GEMM2 stats pass (M-hi only): sum/sumsq atomics (no y write)
//  k5b: GEMM2 (M hi/lo) + fused LayerNorm -> d_out f32 (LDS-staged stores)

#define NB    16
#define DIM   256
#define NSP   4096
#define LED   128
#define HID   256
#define NHEAD 8
#define SCALE 0.17677669529663687f

typedef __bf16 bf16x8 __attribute__((ext_vector_type(8)));
typedef float f32x4 __attribute__((ext_vector_type(4)));
typedef unsigned short us8 __attribute__((ext_vector_type(8)));
typedef unsigned short us4 __attribute__((ext_vector_type(4)));

__device__ __forceinline__ unsigned short f2bf(float f){
  unsigned u = __builtin_bit_cast(unsigned, f);
  u += 0x7fffu + ((u >> 16) & 1u);
  return (unsigned short)(u >> 16);
}
__device__ __forceinline__ float bf2f(unsigned short h){
  unsigned u = ((unsigned)h) << 16;
  return __builtin_bit_cast(float, u);
}
__device__ __forceinline__ bf16x8 ldb8(const unsigned short* p){
  us8 r = *(const us8*)p;
  return __builtin_bit_cast(bf16x8, r);
}
__device__ __forceinline__ f32x4 mfma16(bf16x8 a, bf16x8 b, f32x4 c){
  return __builtin_amdgcn_mfma_f32_16x16x32_bf16(a, b, c, 0, 0, 0);
}
// async global->LDS, 16B per lane; LDS dest = uniform base + lane*16 (linear)
__device__ __forceinline__ void gl16(const unsigned short* g, unsigned short* l){
  __builtin_amdgcn_global_load_lds(
      (const __attribute__((address_space(1))) unsigned int*)g,
      (__attribute__((address_space(3))) unsigned int*)l,
      16, 0, 0);
}

// ---------------- k0: prep (w -> bf16, lk/lq) ----------------
__global__ __launch_bounds__(256) void k0_prep(
    const float* __restrict__ wqkv, const float* __restrict__ cond,
    const float* __restrict__ wlk, const float* __restrict__ blk,
    const float* __restrict__ wlq, const float* __restrict__ blq,
    unsigned short* __restrict__ whi,
    float* __restrict__ lk, float* __restrict__ lq)
{
  const int idx = blockIdx.x*256 + threadIdx.x;
  if (idx < 768*256){
    whi[idx] = f2bf(wqkv[idx]);
  } else {
    int i = idx - 768*256;           // < 8192
    const int which = (i >= NB*HID) ? 1 : 0;
    i &= (NB*HID - 1);
    const int b = i >> 8, o = i & 255;
    const float* wm = which ? wlq : wlk;
    const float* bs = which ? blq : blk;
    float s = bs[o];
    const float* c = cond + b*LED;
    const float* wr = wm + o*LED;
    for (int j=0;j<LED;j++) s += c[j]*wr[j];
    (which ? lq : lk)[i] = s;
  }
}

// ---------------- k1: transpose x -> bf16 ----------------
__global__ __launch_bounds__(256) void k1_txpose(
    const float* __restrict__ x, unsigned short* __restrict__ xt)
{
  __shared__ float tile[64][65];
  const int c0 = blockIdx.x*64, n0 = blockIdx.y*64, b = blockIdx.z;
  const int t = threadIdx.x;
  const int tr = t >> 6, tc = t & 63;
  const float* xp = x + ((size_t)b*DIM + c0)*NSP + n0;
  #pragma unroll
  for (int i=0;i<16;i++){
    const int cl = i*4 + tr;
    tile[cl][tc] = xp[(size_t)cl*NSP + tc];
  }
  __syncthreads();
  unsigned short* xtp = xt + ((size_t)b*NSP + n0)*DIM + c0;
  #pragma unroll
  for (int i=0;i<16;i++){
    const int nl = i*4 + tr;
    xtp[(size_t)nl*DIM + tc] = f2bf(tile[tc][nl]);
  }
}

// ---------------- k2: GEMM1 (qkv) with gload_lds staging + fused epilogues ----------------
__global__ __launch_bounds__(256) void k2_gemm1(
    const unsigned short* __restrict__ whi,
    const unsigned short* __restrict__ xt,
    const float* __restrict__ lkv, const float* __restrict__ lqv,
    unsigned short* __restrict__ qh,
    unsigned short* __restrict__ kexp, unsigned short* __restrict__ vout,
    float* __restrict__ ksum)
{
  __shared__ __align__(16) unsigned char smraw[34816];
  unsigned short* Ah  = (unsigned short*)smraw;            // [128][64] swizzled image
  unsigned short* Bt  = (unsigned short*)(smraw + 16384);  // [128][64]
  unsigned short* stg = (unsigned short*)smraw;            // [128][136] (epilogue alias)

  const int nt = blockIdx.x, mt = blockIdx.y, b = blockIdx.z;
  const int o0 = mt*128, n0 = nt*128;
  const int t = threadIdx.x, lane = t & 63, wv = t >> 6;
  const int wr = wv >> 1, wc = wv & 1;
  const int cl = lane & 15, g = lane >> 4;

  f32x4 acc[4][4];
  const f32x4 z4 = {0.f,0.f,0.f,0.f};
  #pragma unroll
  for (int m=0;m<4;m++)
    #pragma unroll
    for (int n=0;n<4;n++) acc[m][n] = z4;

  const unsigned short* xb = xt + ((size_t)b*NSP + n0)*DIM;
  // gload_lds source swizzle: lane covers row (lane>>3), chunk (lane&7);
  // stored col = chunk*8, so fetch global col 8*(chunk ^ rowbits)
  const int rowc = lane >> 3;
  const int gcol = 8*((lane & 7) ^ rowc);

  for (int kt=0; kt<4; kt++){
    const int k0 = kt*64;
    __syncthreads();                       // prior LDS reads done
    #pragma unroll
    for (int j=0;j<4;j++){
      const int rg = wv*4 + j;             // 8-row group index (0..15)
      const int rr = rg*8 + rowc;
      gl16(&whi[(size_t)(o0+rr)*DIM + k0 + gcol], &Ah[rg*512]);
      gl16(&xb [(size_t)rr*DIM      + k0 + gcol], &Bt[rg*512]);
    }
    __syncthreads();                       // vmcnt(0) drained by barrier
    #pragma unroll
    for (int kk=0; kk<2; kk++){
      const int ko = kk*32 + g*8;
      const int kosw = ko ^ ((cl & 7) << 3);
      bf16x8 a1[4], bb[4];
      #pragma unroll
      for (int m=0;m<4;m++){
        const int row = wr*64 + m*16 + cl;
        a1[m] = ldb8(&Ah[row*64 + kosw]);
      }
      #pragma unroll
      for (int n=0;n<4;n++){
        const int row = wc*64 + n*16 + cl;
        bb[n] = ldb8(&Bt[row*64 + kosw]);
      }
      #pragma unroll
      for (int m=0;m<4;m++)
        #pragma unroll
        for (int n=0;n<4;n++)
          acc[m][n] = mfma16(a1[m], bb[n], acc[m][n]);
    }
  }

  __syncthreads();   // all LDS fragment reads complete before stage reuse

  if (mt < 2){
    // ---- Q: +lq, softmax over d; stage transposed [n_local][dg_local]
    float lqr[4][4];
    #pragma unroll
    for (int m=0;m<4;m++)
      #pragma unroll
      for (int i=0;i<4;i++)
        lqr[m][i] = lqv[b*HID + o0 + wr*64 + m*16 + g*4 + i];
    #pragma unroll
    for (int j=0;j<2;j++){
      #pragma unroll
      for (int nf=0;nf<4;nf++){
        float e[8]; float mx = -1e30f;
        #pragma unroll
        for (int mm=0;mm<2;mm++)
          #pragma unroll
          for (int i=0;i<4;i++){
            const int m = 2*j+mm;
            const float v = acc[m][nf][i] + lqr[m][i];
            e[mm*4+i] = v; mx = fmaxf(mx, v);
          }
        mx = fmaxf(mx, __shfl_xor(mx, 16));
        mx = fmaxf(mx, __shfl_xor(mx, 32));
        float s = 0.f;
        #pragma unroll
        for (int q2=0;q2<8;q2++){ e[q2] = __expf(e[q2]-mx); s += e[q2]; }
        s += __shfl_xor(s, 16);
        s += __shfl_xor(s, 32);
        const float r = 1.f/s;
        const int n_local = wc*64 + nf*16 + cl;
        #pragma unroll
        for (int mm=0;mm<2;mm++){
          const int dg_local = wr*64 + (2*j+mm)*16 + g*4;
          us4 h4;
          #pragma unroll
          for (int i=0;i<4;i++) h4[i] = f2bf(e[mm*4+i]*r);
          *(us4*)&stg[n_local*136 + dg_local] = h4;
        }
      }
    }
    __syncthreads();
    unsigned short* qbase = qh + ((size_t)b*NSP + n0)*HID + o0;
    #pragma unroll
    for (int i2=0;i2<8;i2++){
      const int n_local = wv*32 + i2*4 + (lane>>4);
      const int dg8 = (lane&15)*8;
      us8 val = *(const us8*)&stg[n_local*136 + dg8];
      *(us8*)&qbase[(size_t)n_local*HID + dg8] = val;
    }
  } else {
    // ---- K / V: stage [dg_local][n_local]
    const int isK = (mt < 4);
    const int dgbase = isK ? (mt-2)*128 : (mt-4)*128;
    #pragma unroll
    for (int m=0;m<4;m++)
      #pragma unroll
      for (int i=0;i<4;i++){
        const int dg_local = wr*64 + m*16 + g*4 + i;
        const int nb0 = wc*64 + cl;
        if (isK){
          const float lkval = lkv[b*HID + dgbase + dg_local];
          float s = 0.f;
          #pragma unroll
          for (int nf=0;nf<4;nf++){
            const float v = __expf(acc[m][nf][i] + lkval);
            const unsigned short hh = f2bf(v);
            stg[dg_local*136 + nb0 + nf*16] = hh;
            s += bf2f(hh);
          }
          s += __shfl_xor(s,1); s += __shfl_xor(s,2);
          s += __shfl_xor(s,4); s += __shfl_xor(s,8);
          if (cl == 0) atomicAdd(&ksum[b*HID + dgbase + dg_local], s);
        } else {
          #pragma unroll
          for (int nf=0;nf<4;nf++)
            stg[dg_local*136 + nb0 + nf*16] = f2bf(acc[m][nf][i]);
        }
      }
    __syncthreads();
    unsigned short* obase = (isK ? kexp : vout) + ((size_t)b*HID + dgbase)*NSP + n0;
    #pragma unroll
    for (int i2=0;i2<8;i2++){
      const int dg_local = wv*32 + i2*4 + (lane>>4);
      const int n8 = (lane&15)*8;
      us8 val = *(const us8*)&stg[dg_local*136 + n8];
      *(us8*)&obase[(size_t)dg_local*NSP + n8] = val;
    }
  }
}

// ---------------- k3: context partials ----------------
__global__ __launch_bounds__(256) void k3_ctx(
    const unsigned short* __restrict__ kexp, const unsigned short* __restrict__ vv,
    float* __restrict__ ctxp)
{
  const int half = blockIdx.x, h = blockIdx.y, b = blockIdx.z;
  const int t = threadIdx.x, lane = t&63, wv = t>>6;
  const int cl = lane&15, g = lane>>4;
  const int nstart = half*2048 + wv*512;
  f32x4 acc[2][2];
  const f32x4 z4 = {0.f,0.f,0.f,0.f};
  acc[0][0]=z4; acc[0][1]=z4; acc[1][0]=z4; acc[1][1]=z4;
  const unsigned short* kb = kexp + ((size_t)b*HID + h*32)*NSP;
  const unsigned short* vb = vv   + ((size_t)b*HID + h*32)*NSP;
  for (int ks=0; ks<16; ks++){
    const int k = nstart + ks*32 + g*8;
    bf16x8 a0 = ldb8(&kb[(size_t)(cl)   *NSP + k]);
    bf16x8 a1 = ldb8(&kb[(size_t)(16+cl)*NSP + k]);
    bf16x8 b0 = ldb8(&vb[(size_t)(cl)   *NSP + k]);
    bf16x8 b1 = ldb8(&vb[(size_t)(16+cl)*NSP + k]);
    acc[0][0] = mfma16(a0,b0,acc[0][0]);
    acc[0][1] = mfma16(a0,b1,acc[0][1]);
    acc[1][0] = mfma16(a1,b0,acc[1][0]);
    acc[1][1] = mfma16(a1,b1,acc[1][1]);
  }
  float* outp = ctxp + ((((size_t)b*NHEAD + h)*2 + half)*4 + wv)*1024;
  #pragma unroll
  for (int dm=0;dm<2;dm++)
    #pragma unroll
    for (int em=0;em<2;em++)
      #pragma unroll
      for (int i=0;i<4;i++)
        outp[(dm*16 + g*4 + i)*32 + em*16 + cl] = acc[dm][em][i];
}

// ---------------- k4: M = scale/ksum * (w_out compose context), hi/lo ----------------
__global__ __launch_bounds__(256) void k4_m(
    const float* __restrict__ ctxp, const float* __restrict__ ksum,
    const float* __restrict__ wout,
    unsigned short* __restrict__ mhi, unsigned short* __restrict__ mlo)
{
  const int h = blockIdx.x, b = blockIdx.y;
  __shared__ float ctxl[32][32];
  __shared__ float rkn[32];
  const int t = threadIdx.x;
  const float* base = ctxp + (((size_t)b*NHEAD + h)*8)*1024;
  #pragma unroll
  for (int r=0;r<4;r++){
    const int de = r*256 + t;
    float s = 0.f;
    #pragma unroll
    for (int p=0;p<8;p++) s += base[p*1024 + de];
    ctxl[de>>5][de&31] = s;
  }
  if (t < 32) rkn[t] = SCALE / ksum[b*HID + h*32 + t];
  __syncthreads();
  float w[32];
  const float* wrow = wout + (size_t)t*HID + h*32;
  #pragma unroll
  for (int el=0;el<32;el++) w[el] = wrow[el];
  for (int dl=0; dl<32; dl++){
    float s = 0.f;
    #pragma unroll
    for (int el=0;el<32;el++) s += w[el]*ctxl[dl][el];
    s *= rkn[dl];
    const unsigned short hh = f2bf(s);
    const size_t off = ((size_t)b*HID + t)*HID + h*32 + dl;
    mhi[off] = hh;
    mlo[off] = f2bf(s - bf2f(hh));
  }
}

// ---------------- k5a: GEMM2 stats pass (M-hi only, no y write) ----------------
__global__ __launch_bounds__(256) void k5a_stats(
    const unsigned short* __restrict__ mhi,
    const unsigned short* __restrict__ qhp, const float* __restrict__ bout,
    float* __restrict__ bsum, float* __restrict__ bssq)
{
  __shared__ __align__(16) unsigned char smraw[32768];
  unsigned short* Ah = (unsigned short*)smraw;
  unsigned short* Bh = (unsigned short*)(smraw + 16384);
  __shared__ float red[8];

  const int nt = blockIdx.x, mt = blockIdx.y, b = blockIdx.z;
  const int o0 = mt*128, n0 = nt*128;
  const int t = threadIdx.x, lane = t&63, wv = t>>6;
  const int wr = wv>>1, wc = wv&1;
  const int cl = lane&15, g = lane>>4;

  f32x4 acc[4][4];
  const f32x4 z4 = {0.f,0.f,0.f,0.f};
  #pragma unroll
  for (int m=0;m<4;m++)
    #pragma unroll
    for (int n=0;n<4;n++) acc[m][n] = z4;

  const unsigned short* ab_h = mhi + (size_t)b*HID*HID;
  const unsigned short* bb_h = qhp + ((size_t)b*NSP + n0)*HID;
  const int rowc = lane >> 3;
  const int gcol = 8*((lane & 7) ^ rowc);

  for (int kt=0; kt<4; kt++){
    const int k0 = kt*64;
    __syncthreads();
    #pragma unroll
    for (int j=0;j<4;j++){
      const int rg = wv*4 + j;
      const int rr = rg*8 + rowc;
      gl16(&ab_h[(size_t)(o0+rr)*HID + k0 + gcol], &Ah[rg*512]);
      gl16(&bb_h[(size_t)rr*HID      + k0 + gcol], &Bh[rg*512]);
    }
    __syncthreads();
    #pragma unroll
    for (int kk=0;kk<2;kk++){
      const int ko = kk*32 + g*8;
      const int kosw = ko ^ ((cl & 7) << 3);
      bf16x8 ah[4], bh[4];
      #pragma unroll
      for (int m=0;m<4;m++)
        ah[m] = ldb8(&Ah[(wr*64 + m*16 + cl)*64 + kosw]);
      #pragma unroll
      for (int n=0;n<4;n++)
        bh[n] = ldb8(&Bh[(wc*64 + n*16 + cl)*64 + kosw]);
      #pragma unroll
      for (int m=0;m<4;m++)
        #pragma unroll
        for (int n=0;n<4;n++)
          acc[m][n] = mfma16(ah[m], bh[n], acc[m][n]);
    }
  }

  float lsum = 0.f, lss = 0.f;
  #pragma unroll
  for (int m=0;m<4;m++)
    #pragma unroll
    for (int i=0;i<4;i++){
      const float bo = bout[o0 + wr*64 + m*16 + g*4 + i];
      #pragma unroll
      for (int nf=0;nf<4;nf++){
        const float v = acc[m][nf][i] + bo;
        lsum += v; lss += v*v;
      }
    }
  #pragma unroll
  for (int sft=1; sft<64; sft<<=1){
    lsum += __shfl_xor(lsum, sft);
    lss  += __shfl_xor(lss,  sft);
  }
  if (lane == 0){ red[wv] = lsum; red[4+wv] = lss; }
  __syncthreads();
  if (t == 0){
    atomicAdd(&bsum[b], red[0]+red[1]+red[2]+red[3]);
    atomicAdd(&bssq[b], red[4]+red[5]+red[6]+red[7]);
  }
}

// ---------------- k5b: GEMM2 (hi/lo) + fused LayerNorm write ----------------
__global__ __launch_bounds__(256) void k5b_write(
    const unsigned short* __restrict__ mhi, const unsigned short* __restrict__ mlo,
    const unsigned short* __restrict__ qhp, const float* __restrict__ bout,
    const float* __restrict__ bsum, const float* __restrict__ bssq,
    const float* __restrict__ gamma, const float* __restrict__ beta,
    float* __restrict__ out)
{
  __shared__ __align__(16) unsigned char smraw[49152];
  unsigned short* Ah = (unsigned short*)smraw;             // [128][64]
  unsigned short* Al = (unsigned short*)(smraw + 16384);
  unsigned short* Bh = (unsigned short*)(smraw + 32768);
  float* stg = (float*)smraw;                              // [64][132] alias

  const int nt = blockIdx.x, mt = blockIdx.y, b = blockIdx.z;
  const int o0 = mt*128, n0 = nt*128;
  const int t = threadIdx.x, lane = t&63, wv = t>>6;
  const int wr = wv>>1, wc = wv&1;
  const int cl = lane&15, g = lane>>4;

  f32x4 acc[4][4];
  const f32x4 z4 = {0.f,0.f,0.f,0.f};
  #pragma unroll
  for (int m=0;m<4;m++)
    #pragma unroll
    for (int n=0;n<4;n++) acc[m][n] = z4;

  const unsigned short* ab_h = mhi + (size_t)b*HID*HID;
  const unsigned short* ab_l = mlo + (size_t)b*HID*HID;
  const unsigned short* bb_h = qhp + ((size_t)b*NSP + n0)*HID;
  const int rowc = lane >> 3;
  const int gcol = 8*((lane & 7) ^ rowc);

  for (int kt=0; kt<4; kt++){
    const int k0 = kt*64;
    __syncthreads();
    #pragma unroll
    for (int j=0;j<4;j++){
      const int rg = wv*4 + j;
      const int rr = rg*8 + rowc;
      gl16(&ab_h[(size_t)(o0+rr)*HID + k0 + gcol], &Ah[rg*512]);
      gl16(&ab_l[(size_t)(o0+rr)*HID + k0 + gcol], &Al[rg*512]);
      gl16(&bb_h[(size_t)rr*HID      + k0 + gcol], &Bh[rg*512]);
    }
    __syncthreads();
    #pragma unroll
    for (int kk=0;kk<2;kk++){
      const int ko = kk*32 + g*8;
      const int kosw = ko ^ ((cl & 7) << 3);
      bf16x8 ah[4], al[4], bh[4];
      #pragma unroll
      for (int m=0;m<4;m++){
        const int row = wr*64 + m*16 + cl;
        ah[m] = ldb8(&Ah[row*64 + kosw]);
        al[m] = ldb8(&Al[row*64 + kosw]);
      }
      #pragma unroll
      for (int n=0;n<4;n++){
        const int row = wc*64 + n*16 + cl;
        bh[n] = ldb8(&Bh[row*64 + kosw]);
      }
      #pragma unroll
      for (int m=0;m<4;m++)
        #pragma unroll
        for (int n=0;n<4;n++){
          acc[m][n] = mfma16(ah[m], bh[n], acc[m][n]);
          acc[m][n] = mfma16(al[m], bh[n], acc[m][n]);
        }
    }
  }

  // LN coefficients: out = acc*ga + (beta + (bout-mean)*ga)
  const float inv = 1.f/1048576.f;
  const float mean = bsum[b]*inv;
  const float var  = bssq[b]*inv - mean*mean;
  const float ri = rsqrtf(var + 1e-5f);
  float gav[4][4], bev[4][4];
  #pragma unroll
  for (int m=0;m<4;m++)
    #pragma unroll
    for (int i=0;i<4;i++){
      const int o = o0 + wr*64 + m*16 + g*4 + i;
      const float ga = gamma[o]*ri;
      gav[m][i] = ga;
      bev[m][i] = beta[o] + (bout[o]-mean)*ga;
    }

  // two passes over m-halves; stage [64 rows][132 f32] then 512B-segment stores
  #pragma unroll
  for (int p=0;p<2;p++){
    __syncthreads();
    #pragma unroll
    for (int mm=0;mm<2;mm++){
      const int m = 2*p+mm;
      #pragma unroll
      for (int nf=0;nf<4;nf++)
        #pragma unroll
        for (int i=0;i<4;i++){
          const int lr = wr*32 + mm*16 + g*4 + i;
          stg[lr*132 + wc*64 + nf*16 + cl] = acc[m][nf][i]*gav[m][i] + bev[m][i];
        }
    }
    __syncthreads();
    #pragma unroll
    for (int i2=0;i2<8;i2++){
      const int lr = wv*16 + i2*2 + (lane>>5);
      const int colw = (lane&31)*4;
      f32x4 v = *(const f32x4*)&stg[lr*132 + colw];
      const int dg = o0 + (lr>>5)*64 + p*32 + (lr&31);
      *(f32x4*)&out[((size_t)b*HID + dg)*NSP + n0 + colw] = v;
    }
  }
}

// ---------------- workspace layout (bytes) ----------------
#define OFF_XT     0ull           // ushort [16][4096][256]  32MB
#define OFF_QH     33554432ull    // ushort [16][4096][256]  32MB
#define OFF_CTXP   100663296ull   // float [16][8][2][4][1024] 4MB
#define OFF_MH     104857600ull   // ushort [16][256][256] 2MB
#define OFF_ML     106954752ull
#define OFF_LK     109051904ull   // float [16][256]
#define OFF_LQ     109068288ull
#define OFF_WHI    109084672ull   // ushort [768][256]
#define OFF_KSUM   109871104ull   // float [16][256]
#define OFF_BSUM   109887488ull   // float [16]
#define OFF_BSSQ   109887552ull   // float [16]

extern "C" void kernel_launch(void* const* d_in, const int* in_sizes, int n_in,
                              void* d_out, int out_size, void* d_ws, size_t ws_size,
                              hipStream_t stream) {
  const float* x     = (const float*)d_in[0];
  const float* cond  = (const float*)d_in[1];
  const float* wqkv  = (const float*)d_in[2];
  const float* wlk   = (const float*)d_in[3];
  const float* blk   = (const float*)d_in[4];
  const float* wlq   = (const float*)d_in[5];
  const float* blq   = (const float*)d_in[6];
  const float* wout  = (const float*)d_in[7];
  const float* bout  = (const float*)d_in[8];
  const float* gamma = (const float*)d_in[9];
  const float* beta  = (const float*)d_in[10];

  char* ws = (char*)d_ws;
  unsigned short* xt   = (unsigned short*)(ws + OFF_XT);
  unsigned short* qh   = (unsigned short*)(ws + OFF_QH);
  float*          ctxp = (float*)(ws + OFF_CTXP);
  unsigned short* mhi  = (unsigned short*)(ws + OFF_MH);
  unsigned short* mlo  = (unsigned short*)(ws + OFF_ML);
  float*          lk   = (float*)(ws + OFF_LK);
  float*          lq   = (float*)(ws + OFF_LQ);
  unsigned short* whi  = (unsigned short*)(ws + OFF_WHI);
  float*          ksum = (float*)(ws + OFF_KSUM);
  float*          bsum = (float*)(ws + OFF_BSUM);
  float*          bssq = (float*)(ws + OFF_BSSQ);

  // d_out doubles as scratch for kexp/v (consumed by k3 before k5b writes y)
  unsigned short* kexp = (unsigned short*)d_out;
  unsigned short* vscr = (unsigned short*)d_out + 16777216;
  float*          y    = (float*)d_out;

  hipMemsetAsync(ws + OFF_KSUM, 0, 16384 + 128, stream);

  k0_prep  <<<800, 256, 0, stream>>>(wqkv, cond, wlk, blk, wlq, blq, whi, lk, lq);
  k1_txpose<<<dim3(4,64,16), 256, 0, stream>>>(x, xt);
  k2_gemm1 <<<dim3(32,6,16), 256, 0, stream>>>(whi, xt, lk, lq, qh, kexp, vscr, ksum);
  k3_ctx   <<<dim3(2,8,16), 256, 0, stream>>>(kexp, vscr, ctxp);
  k4_m     <<<dim3(8,16), 256, 0, stream>>>(ctxp, ksum, wout, mhi, mlo);
  k5a_stats<<<dim3(32,2,16), 256, 0, stream>>>(mhi, qh, bout, bsum, bssq);
  k5b_write<<<dim3(32,2,16), 256, 0, stream>>>(mhi, mlo, qh, bout, bsum, bssq, gamma, beta, y);
}